// Round 12
// baseline (79302.417 us; speedup 1.0000x reference)
//
#include <hip/hip_runtime.h>
#include <stdint.h>
#include <math.h>
#include <string.h>

#define Bdim 1024
#define Vdim 256
#define Hdim 1536
#define G4dim 6144
#define Tdim 256
// packed A digits: [d][slot=k/16 (192)][b (1024)][16B]; per-plane bytes (3 planes):
#define APL3 ((size_t)192 * 1024 * 16)

typedef double f64x2 __attribute__((ext_vector_type(2)));
typedef double f64x4 __attribute__((ext_vector_type(4)));
typedef float  f32x4 __attribute__((ext_vector_type(4)));
typedef int    i32x4  __attribute__((ext_vector_type(4)));
typedef int    i32x16 __attribute__((ext_vector_type(16)));

// ---------------- threefry2x32 (JAX default PRNG) ----------------
__device__ __forceinline__ uint32_t rotl32(uint32_t x, uint32_t r) {
    return (x << r) | (x >> (32u - r));
}

__device__ __forceinline__ void tf2x32(uint32_t k0, uint32_t k1, uint32_t x0, uint32_t x1,
                                       uint32_t &o0, uint32_t &o1) {
    uint32_t k2 = k0 ^ k1 ^ 0x1BD11BDAu;
    x0 += k0; x1 += k1;
    x0 += x1; x1 = rotl32(x1, 13); x1 ^= x0;
    x0 += x1; x1 = rotl32(x1, 15); x1 ^= x0;
    x0 += x1; x1 = rotl32(x1, 26); x1 ^= x0;
    x0 += x1; x1 = rotl32(x1, 6);  x1 ^= x0;
    x0 += k1; x1 += k2 + 1u;
    x0 += x1; x1 = rotl32(x1, 17); x1 ^= x0;
    x0 += x1; x1 = rotl32(x1, 29); x1 ^= x0;
    x0 += x1; x1 = rotl32(x1, 16); x1 ^= x0;
    x0 += x1; x1 = rotl32(x1, 24); x1 ^= x0;
    x0 += k2; x1 += k0 + 2u;
    x0 += x1; x1 = rotl32(x1, 13); x1 ^= x0;
    x0 += x1; x1 = rotl32(x1, 15); x1 ^= x0;
    x0 += x1; x1 = rotl32(x1, 26); x1 ^= x0;
    x0 += x1; x1 = rotl32(x1, 6);  x1 ^= x0;
    x0 += k0; x1 += k1 + 3u;
    x0 += x1; x1 = rotl32(x1, 17); x1 ^= x0;
    x0 += x1; x1 = rotl32(x1, 29); x1 ^= x0;
    x0 += x1; x1 = rotl32(x1, 16); x1 ^= x0;
    x0 += x1; x1 = rotl32(x1, 24); x1 ^= x0;
    x0 += k1; x1 += k2 + 4u;
    x0 += x1; x1 = rotl32(x1, 13); x1 ^= x0;
    x0 += x1; x1 = rotl32(x1, 15); x1 ^= x0;
    x0 += x1; x1 = rotl32(x1, 26); x1 ^= x0;
    x0 += x1; x1 = rotl32(x1, 6);  x1 ^= x0;
    x0 += k2; x1 += k0 + 5u;
    o0 = x0; o1 = x1;
}

// ---------------- global_load_lds helper (16B, wave-uniform LDS dest) ----------------
__device__ __forceinline__ void gload_lds16(const void* gsrc, void* ldst) {
    __builtin_amdgcn_global_load_lds(
        (const __attribute__((address_space(1))) uint32_t*)gsrc,
        (__attribute__((address_space(3))) uint32_t*)(uint32_t)(uintptr_t)ldst,
        16, 0, 0);
}

// -------- signed 8-bit digit split (exact two's-complement with carry) --------
__device__ __forceinline__ void digits3(int X, int8_t &d0, int8_t &d1, int8_t &d2) {
    int r = X;
    d2 = (int8_t)r; r = (r - d2) >> 8;
    d1 = (int8_t)r; r = (r - d1) >> 8;
    d0 = (int8_t)r;
}

// ============ MFMA f64 layout calibration probe (fallback path) ============
__global__ void mfma_probe_kernel(int* lutAB, uint32_t* lutD) {
    __shared__ uint32_t rmask[16][2];
    __shared__ uint32_t cmask[16][2];
    __shared__ double Vrow[16];
    __shared__ double Vcol[16];
    __shared__ int row0_ka[4];
    const int l = threadIdx.x;
    const int g = l >> 4, m = l & 15;
    const f64x4 z = {0.0, 0.0, 0.0, 0.0};
    const double one = 1.0;

    double plo = (l < 32) ? ldexp(1.0, l) : 0.0;
    double phi = (l >= 32) ? ldexp(1.0, l - 32) : 0.0;

    f64x4 d1a = __builtin_amdgcn_mfma_f64_16x16x4f64(plo, one, z, 0, 0, 0);
    f64x4 d1b = __builtin_amdgcn_mfma_f64_16x16x4f64(phi, one, z, 0, 0, 0);
    f64x4 d2a = __builtin_amdgcn_mfma_f64_16x16x4f64(one, plo, z, 0, 0, 0);
    f64x4 d2b = __builtin_amdgcn_mfma_f64_16x16x4f64(one, phi, z, 0, 0, 0);

    bool tau = !(d2a[0] == d2a[1] && d2a[0] == d2a[2] && d2a[0] == d2a[3] &&
                 d2b[0] == d2b[1] && d2b[0] == d2b[2] && d2b[0] == d2b[3]);

    if (!tau) {
        if (m == 0)
            for (int r = 0; r < 4; r++) {
                rmask[4 * g + r][0] = (uint32_t)d1a[r];
                rmask[4 * g + r][1] = (uint32_t)d1b[r];
            }
        if (l < 16) { cmask[m][0] = (uint32_t)d2a[0]; cmask[m][1] = (uint32_t)d2b[0]; }
    } else {
        if (l < 16) { rmask[m][0] = (uint32_t)d1a[0]; rmask[m][1] = (uint32_t)d1b[0]; }
        if (m == 0)
            for (int r = 0; r < 4; r++) {
                cmask[4 * g + r][0] = (uint32_t)d2a[r];
                cmask[4 * g + r][1] = (uint32_t)d2b[r];
            }
    }
    __syncthreads();

    int ra = 0, pa = 0, cb = 0, qb = 0;
    for (int i = 0; i < 16; i++) {
        {
            uint32_t lo = rmask[i][0], hi = rmask[i][1];
            bool in = (l < 32) ? ((lo >> l) & 1u) : ((hi >> (l - 32)) & 1u);
            if (in) {
                ra = i;
                uint32_t blo = (l < 32) ? (lo & ((1u << l) - 1u)) : lo;
                uint32_t bhi = (l < 32) ? 0u : (hi & ((1u << (l - 32)) - 1u));
                pa = __popc(blo) + __popc(bhi);
            }
        }
        {
            uint32_t lo = cmask[i][0], hi = cmask[i][1];
            bool in = (l < 32) ? ((lo >> l) & 1u) : ((hi >> (l - 32)) & 1u);
            if (in) {
                cb = i;
                uint32_t blo = (l < 32) ? (lo & ((1u << l) - 1u)) : lo;
                uint32_t bhi = (l < 32) ? 0u : (hi & ((1u << (l - 32)) - 1u));
                qb = __popc(blo) + __popc(bhi);
            }
        }
    }

    f64x4 d3 = __builtin_amdgcn_mfma_f64_16x16x4f64(ldexp(1.0, 8 * pa), ldexp(1.0, 2 * qb), z, 0, 0, 0);

    if (!tau) {
        if (m == 0) for (int r = 0; r < 4; r++) Vrow[4 * g + r] = d3[r];
        if (l < 16) Vcol[m] = d3[0];
    } else {
        if (l < 16) Vrow[m] = d3[0];
        if (m == 0) for (int r = 0; r < 4; r++) Vcol[4 * g + r] = d3[r];
    }
    __syncthreads();

    if (l == 0) {
        uint32_t V = (uint32_t)Vrow[0];
        while (V) { int e = __ffs(V) - 1; V &= V - 1; row0_ka[e >> 3] = (e & 7) >> 1; }
    }
    __syncthreads();

    int ka = 0, kb = 0;
    {
        uint32_t V = (uint32_t)Vrow[ra];
        while (V) { int e = __ffs(V) - 1; V &= V - 1; if ((e >> 3) == pa) ka = (e & 7) >> 1; }
    }
    if (cb == 0) kb = qb;
    else {
        uint32_t V = (uint32_t)Vcol[cb];
        while (V) { int e = __ffs(V) - 1; V &= V - 1; if (((e & 7) >> 1) == qb) kb = row0_ka[e >> 3]; }
    }

    lutAB[l] = ra | (ka << 8) | (cb << 16) | (kb << 24);
    uint32_t pd = 0;
    if (!tau) for (int r = 0; r < 4; r++) { pd |= (uint32_t)(4 * g + r) << (4 * r); pd |= (uint32_t)m << (16 + 4 * r); }
    else      for (int r = 0; r < 4; r++) { pd |= (uint32_t)m << (4 * r); pd |= (uint32_t)(4 * g + r) << (16 + 4 * r); }
    lutD[l] = pd;
}

// ---- f64 MFMA GEMM (fallback path) ----
#define SA 18
#define SB 18
__global__ __launch_bounds__(256, 2)
void gemm_mfma_kernel(const double* __restrict__ A1, const double* __restrict__ A2,
                      const float* __restrict__ W1, const float* __restrict__ W2,
                      double* __restrict__ C, const float* __restrict__ b1,
                      const float* __restrict__ b2, const int* __restrict__ lutAB,
                      const uint32_t* __restrict__ lutD, int Keach, int nParts) {
    __shared__ double As[64][SA];
    __shared__ double Bs[128][SB];
    const int tid  = threadIdx.x;
    const int lane = tid & 63;
    const int w    = tid >> 6;
    const int b0   = blockIdx.x * 64;
    const int n0   = blockIdx.y * 128;

    const int pk = lutAB[lane];
    const int ra = pk & 255;
    const int ka = (pk >> 8) & 255;
    const int cb = (pk >> 16) & 255;
    const int kb = (pk >> 24) & 255;
    const uint32_t pd = lutD[lane];

    const int ar = tid & 63;
    const int akq = tid >> 6;
    const int bn = tid & 127;
    const int bh = tid >> 7;

    f64x4 acc[4][2];
#pragma unroll
    for (int fi = 0; fi < 4; fi++)
#pragma unroll
        for (int fj = 0; fj < 2; fj++) acc[fi][fj] = (f64x4){0.0, 0.0, 0.0, 0.0};

    const int Ktot = Keach * nParts;
    for (int k0 = 0; k0 < Ktot; k0 += 16) {
        const double* Ap = (k0 < Keach) ? A1 : A2;
        const float*  Wp = (k0 < Keach) ? W1 : W2;
        const int kbase = (k0 < Keach) ? k0 : k0 - Keach;

        __syncthreads();
        {
            const double* src = &Ap[(size_t)(b0 + ar) * Hdim + kbase + 4 * akq];
            f64x2 v0 = *(const f64x2*)(src);
            f64x2 v1 = *(const f64x2*)(src + 2);
            *(f64x2*)&As[ar][4 * akq]     = v0;
            *(f64x2*)&As[ar][4 * akq + 2] = v1;
        }
        {
            const float* src = &Wp[(size_t)(n0 + bn) * Keach + kbase + 8 * bh];
            f32x4 u0 = *(const f32x4*)(src);
            f32x4 u1 = *(const f32x4*)(src + 4);
            f64x2 d0 = {(double)u0.x, (double)u0.y};
            f64x2 d1 = {(double)u0.z, (double)u0.w};
            f64x2 d2 = {(double)u1.x, (double)u1.y};
            f64x2 d3 = {(double)u1.z, (double)u1.w};
            *(f64x2*)&Bs[bn][8 * bh]     = d0;
            *(f64x2*)&Bs[bn][8 * bh + 2] = d1;
            *(f64x2*)&Bs[bn][8 * bh + 4] = d2;
            *(f64x2*)&Bs[bn][8 * bh + 6] = d3;
        }
        __syncthreads();

#pragma unroll
        for (int kk = 0; kk < 4; kk++) {
            const int kaI = 4 * kk + ka;
            const int kbI = 4 * kk + kb;
            double a0 = As[ra +  0][kaI];
            double a1 = As[ra + 16][kaI];
            double a2 = As[ra + 32][kaI];
            double a3 = As[ra + 48][kaI];
            double bb0 = Bs[32 * w + cb +  0][kbI];
            double bb1 = Bs[32 * w + cb + 16][kbI];
            acc[0][0] = __builtin_amdgcn_mfma_f64_16x16x4f64(a0, bb0, acc[0][0], 0, 0, 0);
            acc[1][0] = __builtin_amdgcn_mfma_f64_16x16x4f64(a1, bb0, acc[1][0], 0, 0, 0);
            acc[2][0] = __builtin_amdgcn_mfma_f64_16x16x4f64(a2, bb0, acc[2][0], 0, 0, 0);
            acc[3][0] = __builtin_amdgcn_mfma_f64_16x16x4f64(a3, bb0, acc[3][0], 0, 0, 0);
            acc[0][1] = __builtin_amdgcn_mfma_f64_16x16x4f64(a0, bb1, acc[0][1], 0, 0, 0);
            acc[1][1] = __builtin_amdgcn_mfma_f64_16x16x4f64(a1, bb1, acc[1][1], 0, 0, 0);
            acc[2][1] = __builtin_amdgcn_mfma_f64_16x16x4f64(a2, bb1, acc[2][1], 0, 0, 0);
            acc[3][1] = __builtin_amdgcn_mfma_f64_16x16x4f64(a3, bb1, acc[3][1], 0, 0, 0);
        }
    }

#pragma unroll
    for (int fi = 0; fi < 4; fi++) {
#pragma unroll
        for (int fj = 0; fj < 2; fj++) {
#pragma unroll
            for (int r = 0; r < 4; r++) {
                int row = b0 + 16 * fi + (int)((pd >> (4 * r)) & 15u);
                int col = n0 + 32 * w + 16 * fj + (int)((pd >> (16 + 4 * r)) & 15u);
                C[(size_t)row * G4dim + col] = acc[fi][fj][r] + (double)b1[col] + (double)b2[col];
            }
        }
    }
}

// ======== i8 Ozaki-split GEMM (3-digit, 6 products s<=2), tile 128x128, 2 blocks/CU ====
// h = Xh*2^-22, w = Xw*2^-25 (3 signed int8 digits each, MSB first). Diagonals s=i+j<=2
// kept; i32 accumulation exact. gate scale(s) = 2^(-15-8s).
// W packed gate-interleaved pc=4j+g, 128-col panels: [panel48][chunk32][d3][ks2][col128][16B]
//   (12288 B per (panel,chunk)). A packed [d3][slot=k/16][b][16B].
// Tile 128x128, 8 waves (wave: rows 32*(w&3), cols 64*(w>>2); acc[2][3] = 96 VGPR).
// Grid 8x48 = 384 blocks; LDS ring-3 x 24576 = 72KB -> 2 blocks/CU, 4 waves/SIMD
// (launch_bounds(512,4) caps 128 VGPR). Stage = 24 loads = exactly 3/wave; counted
// vmcnt(6)/(3)/(0); single barrier per chunk: [wait][barrier][STAGE(c+2)][compute(c)].
__global__ __launch_bounds__(512, 4)
void gemm_i8_kernel(const int8_t* __restrict__ Apack, const int8_t* __restrict__ Wpack,
                    const double* __restrict__ bsum, float* __restrict__ Gout, int K) {
    __shared__ int8_t lds8[73728];    // ring: 3 x 24576 (A 12288 + B 12288)
    const int tid  = threadIdx.x;
    const int lane = tid & 63;
    const int w    = tid >> 6;

    const int orig = (int)blockIdx.x;
    const int wgid = (orig & 7) * 48 + (orig >> 3);   // XCD-bijective (384 = 48*8)
    const int b0 = (wgid & 7) * 128;
    const int panel = wgid >> 3;              // 0..47
    const int n0 = panel * 128;

    const int wr = w & 3;
    const int wc = w >> 2;                    // 0..1
    const int lm = lane & 31;
    const int lh = lane >> 5;

    const int nc = K >> 5;                    // 48 (L0) or 96 (L1)
    const int8_t* Wp = Wpack + (size_t)panel * nc * 12288;

    i32x16 acc[2][3];
#pragma unroll
    for (int cf = 0; cf < 2; cf++)
#pragma unroll
        for (int s = 0; s < 3; s++)
            acc[cf][s] = (i32x16){0,0,0,0,0,0,0,0,0,0,0,0,0,0,0,0};

    // stage one 32-k chunk: 24 x 1KB contiguous loads, exactly 3 per wave
    auto STAGE = [&](int8_t* buf, int c) {
#pragma unroll
        for (int u = 0; u < 3; u++) {
            const int li = 8 * u + w;         // 0..23
            if (li < 12) {                    // A: (d, ks, half)
                const int d = li >> 2, ks = (li >> 1) & 1, hf = li & 1;
                const int8_t* src = Apack + (size_t)d * APL3
                                  + (((size_t)(c * 2 + ks)) * 1024 + b0 + hf * 64 + lane) * 16;
                gload_lds16(src, buf + ((d * 2 + ks) * 128 + hf * 64) * 16);
            } else {                          // B: (d, ks, half)
                const int bli = li - 12;      // 0..11
                const int d = bli >> 2, rem = bli & 3, ks = rem >> 1, hf = rem & 1;
                const int8_t* src = Wp + (size_t)c * 12288
                                  + ((d * 2 + ks) * 128 + hf * 64 + lane) * 16;
                gload_lds16(src, buf + 12288 + ((d * 2 + ks) * 128 + hf * 64) * 16);
            }
        }
    };

    STAGE(lds8, 0);
    STAGE(lds8 + 24576, 1);

    int cur = 0, stg = 2;
    for (int c = 0; c < nc; c++) {
        // my chunk-c loads done; only chunk-(c+1)'s 3 (and c+2's after STAGE) outstanding
        if (c + 1 < nc) {
            asm volatile("s_waitcnt vmcnt(3)" ::: "memory");
        } else {
            asm volatile("s_waitcnt vmcnt(0)" ::: "memory");
        }
        __builtin_amdgcn_s_barrier();         // all waves: chunk-c in LDS; reads of c-1 done
        if (c + 2 < nc) STAGE(lds8 + stg * 24576, c + 2);

        const int8_t* buf = lds8 + cur * 24576;
        i32x4 a0 = *(const i32x4*)(buf + ((0 * 2 + lh) * 128 + wr * 32 + lm) * 16);
        i32x4 a1 = *(const i32x4*)(buf + ((1 * 2 + lh) * 128 + wr * 32 + lm) * 16);
        i32x4 a2 = *(const i32x4*)(buf + ((2 * 2 + lh) * 128 + wr * 32 + lm) * 16);

        __builtin_amdgcn_s_setprio(1);
#pragma unroll
        for (int cf = 0; cf < 2; cf++) {
            const int bcol = wc * 64 + cf * 32 + lm;
            i32x4 b0v = *(const i32x4*)(buf + 12288 + ((0 * 2 + lh) * 128 + bcol) * 16);
            acc[cf][0] = __builtin_amdgcn_mfma_i32_32x32x32_i8(a0, b0v, acc[cf][0], 0, 0, 0);
            acc[cf][1] = __builtin_amdgcn_mfma_i32_32x32x32_i8(a1, b0v, acc[cf][1], 0, 0, 0);
            acc[cf][2] = __builtin_amdgcn_mfma_i32_32x32x32_i8(a2, b0v, acc[cf][2], 0, 0, 0);
            i32x4 b1v = *(const i32x4*)(buf + 12288 + ((1 * 2 + lh) * 128 + bcol) * 16);
            acc[cf][1] = __builtin_amdgcn_mfma_i32_32x32x32_i8(a0, b1v, acc[cf][1], 0, 0, 0);
            acc[cf][2] = __builtin_amdgcn_mfma_i32_32x32x32_i8(a1, b1v, acc[cf][2], 0, 0, 0);
            i32x4 b2v = *(const i32x4*)(buf + 12288 + ((2 * 2 + lh) * 128 + bcol) * 16);
            acc[cf][2] = __builtin_amdgcn_mfma_i32_32x32x32_i8(a0, b2v, acc[cf][2], 0, 0, 0);
        }
        __builtin_amdgcn_s_setprio(0);

        cur = (cur == 2) ? 0 : cur + 1;
        stg = (stg == 2) ? 0 : stg + 1;
    }

    // epilogue: C/D 32x32 layout (col=lane&31, row=(r&3)+8*(r>>2)+4*(lane>>5));
    // per (cf,r): 32 lanes write 32 consecutive f32 -> 128B coalesced stores.
#pragma unroll
    for (int cf = 0; cf < 2; cf++) {
        const int pc = n0 + wc * 64 + cf * 32 + lm;
        const double bb = bsum[pc];
#pragma unroll
        for (int r = 0; r < 16; r++) {
            const int row = b0 + wr * 32 + (r & 3) + 8 * (r >> 2) + 4 * lh;
            Gout[(size_t)row * G4dim + pc] = (float)(
                  (double)acc[cf][0][r] * 0x1p-15
                + (double)acc[cf][1][r] * 0x1p-23
                + (double)acc[cf][2][r] * 0x1p-31 + bb);
        }
    }
}

// ---------------- LSTM cell (i8 path): f32 gates, f32 c state, f32 transcendentals ----
__global__ __launch_bounds__(256)
void cell_i8_kernel(const float* __restrict__ G, float* __restrict__ c,
                    const float* __restrict__ Wg, const int* __restrict__ idx,
                    int useGather, int8_t* __restrict__ Apack, int koff) {
    int e = blockIdx.x * 256 + threadIdx.x;     // 0 .. B*H-1
    int b = e / Hdim, j = e - b * Hdim;
    const f32x4 gv = *(const f32x4*)(G + (size_t)b * G4dim + 4 * j);
    float gi = gv.x, gf = gv.y, gg = gv.z, go = gv.w;
    if (useGather) {
        const f32x4 wv = *(const f32x4*)(Wg + (size_t)idx[b] * G4dim + 4 * j);
        gi += wv.x; gf += wv.y; gg += wv.z; go += wv.w;
    }
    float si = 1.0f / (1.0f + expf(-gi));
    float sf = 1.0f / (1.0f + expf(-gf));
    float tg = tanhf(gg);
    float so = 1.0f / (1.0f + expf(-go));
    float cn = sf * c[e] + si * tg;
    c[e] = cn;
    float hn = so * tanhf(cn);
    int X = __float2int_rn(hn * 4194304.0f);    // h * 2^22, |h| <= 1
    int8_t q0, q1, q2;
    digits3(X, q0, q1, q2);
    const int slot = (koff + j) >> 4, byte = j & 15;
    const size_t ab = ((size_t)slot * 1024 + b) * 16 + byte;
    Apack[ab]            = q0;
    Apack[APL3 + ab]     = q1;
    Apack[2 * APL3 + ab] = q2;
}

// ======== i8 logits GEMM (3-digit, 6 products, packed): Lpart[ksp][b][v] (f32) ========
__global__ __launch_bounds__(256)
void logits_i8_kernel(const int8_t* __restrict__ Apack, const int8_t* __restrict__ Wodp,
                      float* __restrict__ Lpart) {
    __shared__ int8_t lds8[24576];
    const int tid  = threadIdx.x;
    const int lane = tid & 63;
    const int w    = tid >> 6;
    const int b0   = blockIdx.x * 64;
    const int p    = blockIdx.y;
    const int ksp  = blockIdx.z;

    const int rh = w & 1;
    const int cw = w >> 1;
    const int lm = lane & 31;
    const int lh = lane >> 5;

    i32x16 acc[3];
#pragma unroll
    for (int s = 0; s < 3; s++)
        acc[s] = (i32x16){0,0,0,0,0,0,0,0,0,0,0,0,0,0,0,0};

    for (int c = 0; c < 6; c++) {
        __syncthreads();
#pragma unroll
        for (int u = 0; u < 6; u++) {
            const int li = 4 * u + w;     // 0..23
            if (li < 12) {
                const int d = li >> 2, ks = li & 3;
                const int slot = 96 + ksp * 24 + c * 4 + ks;
                const int8_t* src = Apack + (size_t)d * APL3
                                  + ((size_t)slot * 1024 + b0 + lane) * 16;
                gload_lds16(src, lds8 + li * 1024);
            } else {
                const int bli = li - 12;
                const int d = bli >> 2, ks = bli & 3;
                const int seg = ((p * 24 + ksp * 6 + c) * 3 + d) * 4 + ks;
                const int8_t* src = Wodp + ((size_t)seg * 64 + lane) * 16;
                gload_lds16(src, lds8 + 12288 + bli * 1024);
            }
        }
        __syncthreads();

#pragma unroll
        for (int kk = 0; kk < 2; kk++) {
            const int ks = 2 * kk + lh;
            i32x4 a[3], bb[3];
#pragma unroll
            for (int d = 0; d < 3; d++) {
                a[d]  = *(const i32x4*)(lds8 + ((d * 4 + ks) * 64 + rh * 32 + lm) * 16);
                bb[d] = *(const i32x4*)(lds8 + 12288 + ((d * 4 + ks) * 64 + cw * 32 + lm) * 16);
            }
            acc[0] = __builtin_amdgcn_mfma_i32_32x32x32_i8(a[0], bb[0], acc[0], 0, 0, 0);
            acc[1] = __builtin_amdgcn_mfma_i32_32x32x32_i8(a[0], bb[1], acc[1], 0, 0, 0);
            acc[1] = __builtin_amdgcn_mfma_i32_32x32x32_i8(a[1], bb[0], acc[1], 0, 0, 0);
            acc[2] = __builtin_amdgcn_mfma_i32_32x32x32_i8(a[0], bb[2], acc[2], 0, 0, 0);
            acc[2] = __builtin_amdgcn_mfma_i32_32x32x32_i8(a[1], bb[1], acc[2], 0, 0, 0);
            acc[2] = __builtin_amdgcn_mfma_i32_32x32x32_i8(a[2], bb[0], acc[2], 0, 0, 0);
        }
    }

    const int col = p * 64 + cw * 32 + lm;
#pragma unroll
    for (int r = 0; r < 16; r++) {
        const int row = b0 + rh * 32 + (r & 3) + 8 * (r >> 2) + 4 * lh;
        const double g = (double)acc[0][r] * 0x1p-15
                       + (double)acc[1][r] * 0x1p-23
                       + (double)acc[2][r] * 0x1p-31;
        Lpart[((size_t)ksp * Bdim + row) * Vdim + col] = (float)g;
    }
}

// ---- gate-W 3-digit quantization, gate-interleaved packed (pc = 4j+g), 128-col panels --
// out offset = ((p*NCH + c)*6 + d*2 + ks)*2048 + col*16 + byte   (p = pc/128, col = pc%128)
__global__ __launch_bounds__(256)
void wquant_gate_kernel(const float* __restrict__ W, int8_t* __restrict__ out,
                        int col0, int NCH, int total4) {
    int t = blockIdx.x * 256 + threadIdx.x;
    if (t >= total4) return;
    int n = (4 * t) / Hdim, k = (4 * t) % Hdim;
    f32x4 wv = *(const f32x4*)(W + (size_t)n * Hdim + k);
    uint32_t pk[3] = {0, 0, 0};
#pragma unroll
    for (int l = 0; l < 4; l++) {
        double x = (double)wv[l] * 33554432.0;     // w * 2^25
        x = fmin(fmax(x, -8323072.0), 8323072.0);
        int X = __double2int_rn(x);
        int8_t e0, e1, e2;
        digits3(X, e0, e1, e2);
        pk[0] |= ((uint32_t)(uint8_t)e0) << (8 * l);
        pk[1] |= ((uint32_t)(uint8_t)e1) << (8 * l);
        pk[2] |= ((uint32_t)(uint8_t)e2) << (8 * l);
    }
    const int pcol = 4 * (n % 1536) + n / 1536;
    const int p = pcol >> 7, col = pcol & 127;
    const int kk = col0 + k;
    const int c = kk >> 5, ks = (kk >> 4) & 1, byte = kk & 15;
#pragma unroll
    for (int d = 0; d < 3; d++) {
        size_t off = ((size_t)(p * NCH + c) * 6 + d * 2 + ks) * 2048 + col * 16 + byte;
        *(uint32_t*)(out + off) = pk[d];
    }
}

// ---- W_out 3-digit quantization into packed layout ----
__global__ __launch_bounds__(256)
void wquant_out_kernel(const float* __restrict__ W, int8_t* __restrict__ out, int total4) {
    int t = blockIdx.x * 256 + threadIdx.x;
    if (t >= total4) return;
    int n = (4 * t) / Hdim, k = (4 * t) % Hdim;
    f32x4 wv = *(const f32x4*)(W + (size_t)n * Hdim + k);
    uint32_t pk[3] = {0, 0, 0};
#pragma unroll
    for (int l = 0; l < 4; l++) {
        double x = (double)wv[l] * 33554432.0;
        x = fmin(fmax(x, -8323072.0), 8323072.0);
        int X = __double2int_rn(x);
        int8_t e0, e1, e2;
        digits3(X, e0, e1, e2);
        pk[0] |= ((uint32_t)(uint8_t)e0) << (8 * l);
        pk[1] |= ((uint32_t)(uint8_t)e1) << (8 * l);
        pk[2] |= ((uint32_t)(uint8_t)e2) << (8 * l);
    }
    const int p = n >> 6, col = n & 63;
    const int c = k >> 6, ks = (k >> 4) & 3, byte = k & 15;
#pragma unroll
    for (int d = 0; d < 3; d++) {
        size_t off = ((size_t)((p * 24 + c) * 3 + d) * 4 + ks) * 1024 + col * 16 + byte;
        *(uint32_t*)(out + off) = pk[d];
    }
}

// ---- bias pack: bs[4*j+g] = b1[g*H+j] + b2[g*H+j] ----
__global__ __launch_bounds__(256)
void biaspack_kernel(const float* __restrict__ b1, const float* __restrict__ b2,
                     double* __restrict__ bs) {
    int n = blockIdx.x * 256 + threadIdx.x;
    if (n >= G4dim) return;
    int g = n / Hdim, j = n % Hdim;
    bs[4 * j + g] = (double)b1[n] + (double)b2[n];
}

// ---- W_ih0 transpose into packed cols: Wt[v][4*j+g] = W[g*H+j][v] ----
__global__ __launch_bounds__(256)
void wtrans_kernel(const float* __restrict__ W, float* __restrict__ Wt) {
    __shared__ float tile[32][33];
    const int tx = threadIdx.x & 31, ty = threadIdx.x >> 5;
    const int r0 = blockIdx.x * 32;
    const int c0 = blockIdx.y * 32;
#pragma unroll
    for (int r = 0; r < 4; r++)
        tile[ty + 8 * r][tx] = W[(size_t)(r0 + ty + 8 * r) * Vdim + c0 + tx];
    __syncthreads();
    const int g = r0 / 1536;
#pragma unroll
    for (int r = 0; r < 4; r++) {
        const int n = r0 + tx;
        const int pc = 4 * (n % 1536) + g;
        Wt[(size_t)(c0 + ty + 8 * r) * G4dim + pc] = tile[tx][ty + 8 * r];
    }
}

// ---------------- LSTM cell pointwise update (fallback path only) ----------------
__global__ __launch_bounds__(256)
void cell_kernel(const double* __restrict__ G, double* __restrict__ c,
                 double* __restrict__ hout, const float* __restrict__ Wx,
                 const int* __restrict__ idx, int useGather) {
    int e = blockIdx.x * 256 + threadIdx.x;
    int b = e / Hdim, j = e - b * Hdim;
    size_t gb = (size_t)b * G4dim;
    double gi = G[gb + j];
    double gf = G[gb + Hdim + j];
    double gg = G[gb + 2 * Hdim + j];
    double go = G[gb + 3 * Hdim + j];
    if (useGather) {
        int id = idx[b];
        gi += (double)Wx[(size_t)(0 * Hdim + j) * Vdim + id];
        gf += (double)Wx[(size_t)(1 * Hdim + j) * Vdim + id];
        gg += (double)Wx[(size_t)(2 * Hdim + j) * Vdim + id];
        go += (double)Wx[(size_t)(3 * Hdim + j) * Vdim + id];
    }
    double si = 1.0 / (1.0 + exp(-gi));
    double sf = 1.0 / (1.0 + exp(-gf));
    double tg = tanh(gg);
    double so = 1.0 / (1.0 + exp(-go));
    double cn = sf * c[e] + si * tg;
    c[e] = cn;
    hout[e] = so * tanh(cn);
}

// ---- f64 vector GEMM (fallback noise t=0, plain cols) ----
__global__ __launch_bounds__(256)
void gemm_kernel(const float* __restrict__ A, const float* __restrict__ W,
                 double* __restrict__ C, int K) {
    __shared__ double As[16][65];
    __shared__ float  Wsf[16][68];
    const int tid = threadIdx.x;
    const int b0 = blockIdx.x * 64;
    const int n0 = blockIdx.y * 64;
    const int tm = tid >> 4;
    const int tn = tid & 15;

    double acc[4][4];
#pragma unroll
    for (int i = 0; i < 4; i++)
#pragma unroll
        for (int j = 0; j < 4; j++) acc[i][j] = 0.0;

    for (int k0 = 0; k0 < K; k0 += 16) {
        __syncthreads();
#pragma unroll
        for (int l = 0; l < 4; l++) {
            int e = tid + l * 256;
            int i = e >> 4, k = e & 15;
            As[k][i] = (double)A[(size_t)(b0 + i) * K + k0 + k];
            Wsf[k][i] = W[(size_t)(n0 + i) * K + k0 + k];
        }
        __syncthreads();
#pragma unroll
        for (int k = 0; k < 16; k++) {
            double a0 = As[k][tm * 4 + 0];
            double a1 = As[k][tm * 4 + 1];
            double a2 = As[k][tm * 4 + 2];
            double a3 = As[k][tm * 4 + 3];
            double w0 = (double)Wsf[k][tn * 4 + 0];
            double w1 = (double)Wsf[k][tn * 4 + 1];
            double w2 = (double)Wsf[k][tn * 4 + 2];
            double w3 = (double)Wsf[k][tn * 4 + 3];
            acc[0][0] = fma(a0, w0, acc[0][0]); acc[0][1] = fma(a0, w1, acc[0][1]);
            acc[0][2] = fma(a0, w2, acc[0][2]); acc[0][3] = fma(a0, w3, acc[0][3]);
            acc[1][0] = fma(a1, w0, acc[1][0]); acc[1][1] = fma(a1, w1, acc[1][1]);
            acc[1][2] = fma(a1, w2, acc[1][2]); acc[1][3] = fma(a1, w3, acc[1][3]);
            acc[2][0] = fma(a2, w0, acc[2][0]); acc[2][1] = fma(a2, w1, acc[2][1]);
            acc[2][2] = fma(a2, w2, acc[2][2]); acc[2][3] = fma(a2, w3, acc[2][3]);
            acc[3][0] = fma(a3, w0, acc[3][0]); acc[3][1] = fma(a3, w1, acc[3][1]);
            acc[3][2] = fma(a3, w2, acc[3][2]); acc[3][3] = fma(a3, w3, acc[3][3]);
        }
    }

#pragma unroll
    for (int i = 0; i < 4; i++) {
        int row = b0 + tm * 4 + i;
#pragma unroll
        for (int j = 0; j < 4; j++) {
            int col = n0 + tn * 4 + j;
            C[(size_t)row * G4dim + col] += acc[i][j];
        }
    }
}

// ---- f32 noise GEMM (i8 path, t=0): G[row][4j+g] += noise @ W_ih0^T ----
__global__ __launch_bounds__(256)
void gemm_noise_f32(const float* __restrict__ A, const float* __restrict__ W,
                    float* __restrict__ C, int K) {
    __shared__ double As[16][65];
    __shared__ float  Wsf[16][68];
    const int tid = threadIdx.x;
    const int b0 = blockIdx.x * 64;
    const int n0 = blockIdx.y * 64;
    const int tm = tid >> 4;
    const int tn = tid & 15;

    double acc[4][4];
#pragma unroll
    for (int i = 0; i < 4; i++)
#pragma unroll
        for (int j = 0; j < 4; j++) acc[i][j] = 0.0;

    for (int k0 = 0; k0 < K; k0 += 16) {
        __syncthreads();
#pragma unroll
        for (int l = 0; l < 4; l++) {
            int e = tid + l * 256;
            int i = e >> 4, k = e & 15;
            As[k][i] = (double)A[(size_t)(b0 + i) * K + k0 + k];
            Wsf[k][i] = W[(size_t)(n0 + i) * K + k0 + k];
        }
        __syncthreads();
#pragma unroll
        for (int k = 0; k < 16; k++) {
            double a0 = As[k][tm * 4 + 0];
            double a1 = As[k][tm * 4 + 1];
            double a2 = As[k][tm * 4 + 2];
            double a3 = As[k][tm * 4 + 3];
            double w0 = (double)Wsf[k][tn * 4 + 0];
            double w1 = (double)Wsf[k][tn * 4 + 1];
            double w2 = (double)Wsf[k][tn * 4 + 2];
            double w3 = (double)Wsf[k][tn * 4 + 3];
            acc[0][0] = fma(a0, w0, acc[0][0]); acc[0][1] = fma(a0, w1, acc[0][1]);
            acc[0][2] = fma(a0, w2, acc[0][2]); acc[0][3] = fma(a0, w3, acc[0][3]);
            acc[1][0] = fma(a1, w0, acc[1][0]); acc[1][1] = fma(a1, w1, acc[1][1]);
            acc[1][2] = fma(a1, w2, acc[1][2]); acc[1][3] = fma(a1, w3, acc[1][3]);
            acc[2][0] = fma(a2, w0, acc[2][0]); acc[2][1] = fma(a2, w1, acc[2][1]);
            acc[2][2] = fma(a2, w2, acc[2][2]); acc[2][3] = fma(a2, w3, acc[2][3]);
            acc[3][0] = fma(a3, w0, acc[3][0]); acc[3][1] = fma(a3, w1, acc[3][1]);
            acc[3][2] = fma(a3, w2, acc[3][2]); acc[3][3] = fma(a3, w3, acc[3][3]);
        }
    }

#pragma unroll
    for (int i = 0; i < 4; i++) {
        int row = b0 + tm * 4 + i;
#pragma unroll
        for (int j = 0; j < 4; j++) {
            int col = n0 + tn * 4 + j;
            int oc = 4 * (col % 1536) + col / 1536;
            C[(size_t)row * G4dim + oc] += (float)acc[i][j];
        }
    }
}

// -- light sampler: sum split-K partials (f32) + bias + gumbel + argmax --
__global__ __launch_bounds__(256)
void sample_lite_kernel(const float* __restrict__ Lpart, const float* __restrict__ bout,
                        const int* __restrict__ seqlen, int* __restrict__ idx,
                        int* __restrict__ out, int t) {
    __shared__ double rz[256];
    __shared__ int    rv[256];
    const int b = blockIdx.x;
    const int v = threadIdx.x;
    const size_t o = (size_t)b * Vdim + v;
    const size_t P = (size_t)Bdim * Vdim;

    double z = (double)Lpart[o] + (double)Lpart[P + o] + (double)Lpart[2 * P + o]
             + (double)Lpart[3 * P + o] + (double)bout[v];

    uint32_t kt0, kt1;
    tf2x32(0u, 42u, 0u, (uint32_t)t, kt0, kt1);
    uint32_t m = (uint32_t)(b * Vdim + v);
    uint32_t o0, o1;
    tf2x32(kt0, kt1, 0u, m, o0, o1);
    uint32_t bits = o0 ^ o1;
    float f = __uint_as_float((bits >> 9) | 0x3f800000u) - 1.0f;
    double u = (f > 0.f) ? (double)f : (double)1.1754943508222875e-38f;
    float gum32 = (float)(-log(-log(u)));
    z += (double)gum32;

    rz[v] = z; rv[v] = v;
    __syncthreads();
    for (int s = 128; s > 0; s >>= 1) {
        if (v < s) {
            double zo = rz[v + s]; int vo = rv[v + s];
            if (zo > rz[v] || (zo == rz[v] && vo < rv[v])) { rz[v] = zo; rv[v] = vo; }
        }
        __syncthreads();
    }
    if (v == 0) {
        int wv = rv[0];
        idx[b] = wv;
        out[(size_t)t * Bdim + b] = (t < seqlen[b]) ? wv : 0;
    }
}

// -- f64-path sampler (fallback) --
__global__ __launch_bounds__(256)
void sample_kernel(const double* __restrict__ h1, const float* __restrict__ Wout,
                   const float* __restrict__ bout, const int* __restrict__ seqlen,
                   int* __restrict__ idx, int* __restrict__ out, int t) {
    __shared__ double hs[Hdim];
    __shared__ float  Ws[256][33];
    __shared__ double rz[256];
    __shared__ int    rv[256];
    const int b = blockIdx.x;
    const int v = threadIdx.x;

    for (int k = v; k < Hdim; k += 256) hs[k] = h1[(size_t)b * Hdim + k];

    double acc = 0.0;
    for (int kc = 0; kc < Hdim; kc += 32) {
        __syncthreads();
#pragma unroll
        for (int l = 0; l < 32; l++) {
            int e = v + l * 256;
            int vv = e >> 5, kk = e & 31;
            Ws[vv][kk] = Wout[(size_t)vv * Hdim + kc + kk];
        }
        __syncthreads();
#pragma unroll
        for (int kk = 0; kk < 32; kk++)
            acc = fma((double)Ws[v][kk], hs[kc + kk], acc);
    }

    double z = acc + (double)bout[v];

    uint32_t kt0, kt1;
    tf2x32(0u, 42u, 0u, (uint32_t)t, kt0, kt1);
    uint32_t m = (uint32_t)(b * Vdim + v);
    uint32_t o0, o1;
    tf2x32(kt0, kt1, 0u, m, o0, o1);
    uint32_t bits = o0 ^ o1;
    float f = __uint_as_float((bits >> 9) | 0x3f800000u) - 1.0f;
    double u = (f > 0.f) ? (double)f : (double)1.1754943508222875e-38f;
    float gum32 = (float)(-log(-log(u)));
    z += (double)gum32;

    rz[v] = z; rv[v] = v;
    __syncthreads();
    for (int s = 128; s > 0; s >>= 1) {
        if (v < s) {
            double zo = rz[v + s]; int vo = rv[v + s];
            if (zo > rz[v] || (zo == rz[v] && vo < rv[v])) { rz[v] = zo; rv[v] = vo; }
        }
        __syncthreads();
    }
    if (v == 0) {
        int wv = rv[0];
        idx[b] = wv;
        out[(size_t)t * Bdim + b] = (t < seqlen[b]) ? wv : 0;
    }
}

// ---------------- diagnostic sentinel ----------------
__global__ void sentinel_kernel(int* out, int n, int val) {
    int i = blockIdx.x * 256 + threadIdx.x;
    if (i < n) out[i] = val;
}

// ---------------- host orchestration ----------------
extern "C" void kernel_launch(void* const* d_in, const int* in_sizes, int n_in,
                              void* d_out, int out_size, void* d_ws, size_t ws_size,
                              hipStream_t stream) {
    int* out = (int*)d_out;

    const size_t base_dbl = ((size_t)Bdim * G4dim + 4ull * Bdim * Hdim) * sizeof(double);
    const size_t misc = 8192;
    const size_t needed_f64 = base_dbl + misc;
    const size_t apk_sz   = 3ull * APL3;                         // 9.4 MB
    const size_t wd0_sz   = 3ull * G4dim * Hdim;                 // 28.3 MB
    const size_t wd1_sz   = 3ull * G4dim * (2 * Hdim);           // 56.6 MB
    const size_t wod_sz   = 3ull * Vdim * Hdim;                  // 1.18 MB
    const size_t lpart_sz = 4ull * Bdim * Vdim * sizeof(double); // 8.4 MB (f32 uses half)
    const size_t wt_sz    = (size_t)Vdim * G4dim * sizeof(float);// 6.3 MB
    const size_t bs_sz    = (size_t)G4dim * sizeof(double);
    const size_t needed_i8 = needed_f64 + apk_sz + wd0_sz + wd1_sz + wod_sz
                           + lpart_sz + wt_sz + 2 * bs_sz;

    if (ws_size < needed_f64) {
        sentinel_kernel<<<(out_size + 255) / 256, 256, 0, stream>>>(out, out_size, 1000000);
        return;
    }
    const int expect[12] = {Bdim * Vdim, Bdim, G4dim * Vdim, G4dim * Hdim, G4dim, G4dim,
                            G4dim * Hdim, G4dim * Hdim, G4dim, G4dim, Vdim * Hdim, Vdim};
    bool ok = (n_in == 12);
    for (int i = 0; ok && i < 12; i++) ok = (in_sizes[i] == expect[i]);
    if (!ok) {
        sentinel_kernel<<<(out_size + 255) / 256, 256, 0, stream>>>(out, out_size, 2000000);
        return;
    }

    const float* noise  = (const float*)d_in[0];
    const int*   seqlen = (const int*)d_in[1];
    const float* W_ih0  = (const float*)d_in[2];
    const float* W_hh0  = (const float*)d_in[3];
    const float* b_ih0  = (const float*)d_in[4];
    const float* b_hh0  = (const float*)d_in[5];
    const float* W_ih1  = (const float*)d_in[6];
    const float* W_hh1  = (const float*)d_in[7];
    const float* b_ih1  = (const float*)d_in[8];
    const float* b_hh1  = (const float*)d_in[9];
    const float* W_out  = (const float*)d_in[10];
    const float* b_out  = (const float*)d_in[11];

    double* G  = (double*)d_ws;
    double* h0 = G  + (size_t)Bdim * G4dim;
    double* c0 = h0 + (size_t)Bdim * Hdim;
    double* h1 = c0 + (size_t)Bdim * Hdim;
    double* c1 = h1 + (size_t)Bdim * Hdim;
    int*   idx = (int*)(c1 + (size_t)Bdim * Hdim);
    int*  lutAB = idx + Bdim;
    uint32_t* lutD = (uint32_t*)(lutAB + 64);
    int8_t* Apack = (int8_t*)(lutD + 64);
    int8_t* Wd0  = Apack + apk_sz;
    int8_t* Wd1  = Wd0 + wd0_sz;
    int8_t* Wod  = Wd1 + wd1_sz;
    double* Lpart = (double*)(Wod + wod_sz);
    float*  Wih0t = (float*)(Lpart + 4ull * Bdim * Vdim);
    double* bs0  = (double*)(Wih0t + (size_t)Vdim * G4dim);
    double* bs1  = bs0 + G4dim;

    float* Gf = (float*)G;              // i8 path uses G region as f32
    float* Lpf = (float*)Lpart;         // i8 path uses Lpart region as f32
    float* cf0 = (float*)c0;            // i8 path: f32 c state (region zeroed below)
    float* cf1 = (float*)c1;

    const bool use_i8 = (ws_size >= needed_i8);

    (void)hipMemsetAsync(h0, 0, (size_t)4 * Bdim * Hdim * sizeof(double), stream);

    dim3 gOld(Bdim / 64, G4dim / 64);

    if (use_i8) {
        (void)hipMemsetAsync(Apack, 0, apk_sz, stream);
        const int nq = G4dim * Hdim / 4;
        wquant_gate_kernel<<<(nq + 255) / 256, 256, 0, stream>>>(W_hh0, Wd0, 0, 48, nq);
        wquant_gate_kernel<<<(nq + 255) / 256, 256, 0, stream>>>(W_ih1, Wd1, 0, 96, nq);
        wquant_gate_kernel<<<(nq + 255) / 256, 256, 0, stream>>>(W_hh1, Wd1, Hdim, 96, nq);
        const int nqo = Vdim * Hdim / 4;
        wquant_out_kernel<<<(nqo + 255) / 256, 256, 0, stream>>>(W_out, Wod, nqo);
        wtrans_kernel<<<dim3(G4dim / 32, Vdim / 32), 256, 0, stream>>>(W_ih0, Wih0t);
        biaspack_kernel<<<G4dim / 256, 256, 0, stream>>>(b_ih0, b_hh0, bs0);
        biaspack_kernel<<<G4dim / 256, 256, 0, stream>>>(b_ih1, b_hh1, bs1);

        for (int t = 0; t < Tdim; t++) {
            // L0 gates: Gf[row][4j+g] = h0_old @ W_hh0^T + bias (f32, packed cols)
            gemm_i8_kernel<<<384, 512, 0, stream>>>(Apack, Wd0, bs0, Gf, Hdim);
            if (t == 0)   // x = noise: f64-acc GEMM adds into packed f32 G, once
                gemm_noise_f32<<<gOld, 256, 0, stream>>>(noise, W_ih0, Gf, Vdim);
            // cell L0: f32 gates + gather + f32 activations; writes h0 digits (slots 0..95)
            cell_i8_kernel<<<Bdim * Hdim / 256, 256, 0, stream>>>(Gf, cf0, Wih0t, idx,
                                                                  t > 0 ? 1 : 0, Apack, 0);
            // L1 gates: h0_new (slots 0..95) | h1_old (slots 96..191), K=3072 merged
            gemm_i8_kernel<<<384, 512, 0, stream>>>(Apack, Wd1, bs1, Gf, 2 * Hdim);
            // cell L1: writes h1 digits (slots 96..191)
            cell_i8_kernel<<<Bdim * Hdim / 256, 256, 0, stream>>>(Gf, cf1, nullptr, nullptr,
                                                                  0, Apack, Hdim);
            // logits via i8 split-K GEMM (f32 partials), then light sampler
            logits_i8_kernel<<<dim3(16, 4, 4), 256, 0, stream>>>(Apack, Wod, Lpf);
            sample_lite_kernel<<<Bdim, 256, 0, stream>>>(Lpf, b_out, seqlen, idx, out, t);
        }
    } else {
        mfma_probe_kernel<<<1, 64, 0, stream>>>(lutAB, lutD);
        dim3 gM(Bdim / 64, G4dim / 128);
        for (int t = 0; t < Tdim; t++) {
            gemm_mfma_kernel<<<gM, 256, 0, stream>>>(h0, h0, W_hh0, W_hh0, G, b_ih0, b_hh0,
                                                     lutAB, lutD, Hdim, 1);
            if (t == 0)
                gemm_kernel<<<gOld, 256, 0, stream>>>(noise, W_ih0, G, Vdim);
            cell_kernel<<<Bdim * Hdim / 256, 256, 0, stream>>>(G, c0, h0, W_ih0, idx,
                                                               t > 0 ? 1 : 0);
            gemm_mfma_kernel<<<gM, 256, 0, stream>>>(h0, h1, W_ih1, W_hh1, G, b_ih1, b_hh1,
                                                     lutAB, lutD, Hdim, 2);
            cell_kernel<<<Bdim * Hdim / 256, 256, 0, stream>>>(G, c1, h1, nullptr, nullptr, 0);
            sample_kernel<<<Bdim, 256, 0, stream>>>(h1, W_out, b_out, seqlen, idx, out, t);
        }
    }
}

// Round 13
// 49832.431 us; speedup vs baseline: 1.5914x; 1.5914x over previous
//
#include <hip/hip_runtime.h>
#include <stdint.h>
#include <math.h>
#include <string.h>

#define Bdim 1024
#define Vdim 256
#define Hdim 1536
#define G4dim 6144
#define Tdim 256
// packed A digits: [d][slot=k/16 (192)][b (1024)][16B]; per-plane bytes (3 planes):
#define APL3 ((size_t)192 * 1024 * 16)

typedef double f64x2 __attribute__((ext_vector_type(2)));
typedef double f64x4 __attribute__((ext_vector_type(4)));
typedef float  f32x4 __attribute__((ext_vector_type(4)));
typedef int    i32x4  __attribute__((ext_vector_type(4)));
typedef int    i32x16 __attribute__((ext_vector_type(16)));

// ---------------- threefry2x32 (JAX default PRNG) ----------------
__device__ __forceinline__ uint32_t rotl32(uint32_t x, uint32_t r) {
    return (x << r) | (x >> (32u - r));
}

__device__ __forceinline__ void tf2x32(uint32_t k0, uint32_t k1, uint32_t x0, uint32_t x1,
                                       uint32_t &o0, uint32_t &o1) {
    uint32_t k2 = k0 ^ k1 ^ 0x1BD11BDAu;
    x0 += k0; x1 += k1;
    x0 += x1; x1 = rotl32(x1, 13); x1 ^= x0;
    x0 += x1; x1 = rotl32(x1, 15); x1 ^= x0;
    x0 += x1; x1 = rotl32(x1, 26); x1 ^= x0;
    x0 += x1; x1 = rotl32(x1, 6);  x1 ^= x0;
    x0 += k1; x1 += k2 + 1u;
    x0 += x1; x1 = rotl32(x1, 17); x1 ^= x0;
    x0 += x1; x1 = rotl32(x1, 29); x1 ^= x0;
    x0 += x1; x1 = rotl32(x1, 16); x1 ^= x0;
    x0 += x1; x1 = rotl32(x1, 24); x1 ^= x0;
    x0 += k2; x1 += k0 + 2u;
    x0 += x1; x1 = rotl32(x1, 13); x1 ^= x0;
    x0 += x1; x1 = rotl32(x1, 15); x1 ^= x0;
    x0 += x1; x1 = rotl32(x1, 26); x1 ^= x0;
    x0 += x1; x1 = rotl32(x1, 6);  x1 ^= x0;
    x0 += k0; x1 += k1 + 3u;
    x0 += x1; x1 = rotl32(x1, 17); x1 ^= x0;
    x0 += x1; x1 = rotl32(x1, 29); x1 ^= x0;
    x0 += x1; x1 = rotl32(x1, 16); x1 ^= x0;
    x0 += x1; x1 = rotl32(x1, 24); x1 ^= x0;
    x0 += k1; x1 += k2 + 4u;
    x0 += x1; x1 = rotl32(x1, 13); x1 ^= x0;
    x0 += x1; x1 = rotl32(x1, 15); x1 ^= x0;
    x0 += x1; x1 = rotl32(x1, 26); x1 ^= x0;
    x0 += x1; x1 = rotl32(x1, 6);  x1 ^= x0;
    x0 += k2; x1 += k0 + 5u;
    o0 = x0; o1 = x1;
}

// ---------------- global_load_lds helper (16B, wave-uniform LDS dest) ----------------
__device__ __forceinline__ void gload_lds16(const void* gsrc, void* ldst) {
    __builtin_amdgcn_global_load_lds(
        (const __attribute__((address_space(1))) uint32_t*)gsrc,
        (__attribute__((address_space(3))) uint32_t*)(uint32_t)(uintptr_t)ldst,
        16, 0, 0);
}

// -------- signed 8-bit digit split (exact two's-complement with carry) --------
__device__ __forceinline__ void digits3(int X, int8_t &d0, int8_t &d1, int8_t &d2) {
    int r = X;
    d2 = (int8_t)r; r = (r - d2) >> 8;
    d1 = (int8_t)r; r = (r - d1) >> 8;
    d0 = (int8_t)r;
}

// ============ MFMA f64 layout calibration probe (fallback path) ============
__global__ void mfma_probe_kernel(int* lutAB, uint32_t* lutD) {
    __shared__ uint32_t rmask[16][2];
    __shared__ uint32_t cmask[16][2];
    __shared__ double Vrow[16];
    __shared__ double Vcol[16];
    __shared__ int row0_ka[4];
    const int l = threadIdx.x;
    const int g = l >> 4, m = l & 15;
    const f64x4 z = {0.0, 0.0, 0.0, 0.0};
    const double one = 1.0;

    double plo = (l < 32) ? ldexp(1.0, l) : 0.0;
    double phi = (l >= 32) ? ldexp(1.0, l - 32) : 0.0;

    f64x4 d1a = __builtin_amdgcn_mfma_f64_16x16x4f64(plo, one, z, 0, 0, 0);
    f64x4 d1b = __builtin_amdgcn_mfma_f64_16x16x4f64(phi, one, z, 0, 0, 0);
    f64x4 d2a = __builtin_amdgcn_mfma_f64_16x16x4f64(one, plo, z, 0, 0, 0);
    f64x4 d2b = __builtin_amdgcn_mfma_f64_16x16x4f64(one, phi, z, 0, 0, 0);

    bool tau = !(d2a[0] == d2a[1] && d2a[0] == d2a[2] && d2a[0] == d2a[3] &&
                 d2b[0] == d2b[1] && d2b[0] == d2b[2] && d2b[0] == d2b[3]);

    if (!tau) {
        if (m == 0)
            for (int r = 0; r < 4; r++) {
                rmask[4 * g + r][0] = (uint32_t)d1a[r];
                rmask[4 * g + r][1] = (uint32_t)d1b[r];
            }
        if (l < 16) { cmask[m][0] = (uint32_t)d2a[0]; cmask[m][1] = (uint32_t)d2b[0]; }
    } else {
        if (l < 16) { rmask[m][0] = (uint32_t)d1a[0]; rmask[m][1] = (uint32_t)d1b[0]; }
        if (m == 0)
            for (int r = 0; r < 4; r++) {
                cmask[4 * g + r][0] = (uint32_t)d2a[r];
                cmask[4 * g + r][1] = (uint32_t)d2b[r];
            }
    }
    __syncthreads();

    int ra = 0, pa = 0, cb = 0, qb = 0;
    for (int i = 0; i < 16; i++) {
        {
            uint32_t lo = rmask[i][0], hi = rmask[i][1];
            bool in = (l < 32) ? ((lo >> l) & 1u) : ((hi >> (l - 32)) & 1u);
            if (in) {
                ra = i;
                uint32_t blo = (l < 32) ? (lo & ((1u << l) - 1u)) : lo;
                uint32_t bhi = (l < 32) ? 0u : (hi & ((1u << (l - 32)) - 1u));
                pa = __popc(blo) + __popc(bhi);
            }
        }
        {
            uint32_t lo = cmask[i][0], hi = cmask[i][1];
            bool in = (l < 32) ? ((lo >> l) & 1u) : ((hi >> (l - 32)) & 1u);
            if (in) {
                cb = i;
                uint32_t blo = (l < 32) ? (lo & ((1u << l) - 1u)) : lo;
                uint32_t bhi = (l < 32) ? 0u : (hi & ((1u << (l - 32)) - 1u));
                qb = __popc(blo) + __popc(bhi);
            }
        }
    }

    f64x4 d3 = __builtin_amdgcn_mfma_f64_16x16x4f64(ldexp(1.0, 8 * pa), ldexp(1.0, 2 * qb), z, 0, 0, 0);

    if (!tau) {
        if (m == 0) for (int r = 0; r < 4; r++) Vrow[4 * g + r] = d3[r];
        if (l < 16) Vcol[m] = d3[0];
    } else {
        if (l < 16) Vrow[m] = d3[0];
        if (m == 0) for (int r = 0; r < 4; r++) Vcol[4 * g + r] = d3[r];
    }
    __syncthreads();

    if (l == 0) {
        uint32_t V = (uint32_t)Vrow[0];
        while (V) { int e = __ffs(V) - 1; V &= V - 1; row0_ka[e >> 3] = (e & 7) >> 1; }
    }
    __syncthreads();

    int ka = 0, kb = 0;
    {
        uint32_t V = (uint32_t)Vrow[ra];
        while (V) { int e = __ffs(V) - 1; V &= V - 1; if ((e >> 3) == pa) ka = (e & 7) >> 1; }
    }
    if (cb == 0) kb = qb;
    else {
        uint32_t V = (uint32_t)Vcol[cb];
        while (V) { int e = __ffs(V) - 1; V &= V - 1; if (((e & 7) >> 1) == qb) kb = row0_ka[e >> 3]; }
    }

    lutAB[l] = ra | (ka << 8) | (cb << 16) | (kb << 24);
    uint32_t pd = 0;
    if (!tau) for (int r = 0; r < 4; r++) { pd |= (uint32_t)(4 * g + r) << (4 * r); pd |= (uint32_t)m << (16 + 4 * r); }
    else      for (int r = 0; r < 4; r++) { pd |= (uint32_t)m << (4 * r); pd |= (uint32_t)(4 * g + r) << (16 + 4 * r); }
    lutD[l] = pd;
}

// ---- f64 MFMA GEMM (fallback path) ----
#define SA 18
#define SB 18
__global__ __launch_bounds__(256, 2)
void gemm_mfma_kernel(const double* __restrict__ A1, const double* __restrict__ A2,
                      const float* __restrict__ W1, const float* __restrict__ W2,
                      double* __restrict__ C, const float* __restrict__ b1,
                      const float* __restrict__ b2, const int* __restrict__ lutAB,
                      const uint32_t* __restrict__ lutD, int Keach, int nParts) {
    __shared__ double As[64][SA];
    __shared__ double Bs[128][SB];
    const int tid  = threadIdx.x;
    const int lane = tid & 63;
    const int w    = tid >> 6;
    const int b0   = blockIdx.x * 64;
    const int n0   = blockIdx.y * 128;

    const int pk = lutAB[lane];
    const int ra = pk & 255;
    const int ka = (pk >> 8) & 255;
    const int cb = (pk >> 16) & 255;
    const int kb = (pk >> 24) & 255;
    const uint32_t pd = lutD[lane];

    const int ar = tid & 63;
    const int akq = tid >> 6;
    const int bn = tid & 127;
    const int bh = tid >> 7;

    f64x4 acc[4][2];
#pragma unroll
    for (int fi = 0; fi < 4; fi++)
#pragma unroll
        for (int fj = 0; fj < 2; fj++) acc[fi][fj] = (f64x4){0.0, 0.0, 0.0, 0.0};

    const int Ktot = Keach * nParts;
    for (int k0 = 0; k0 < Ktot; k0 += 16) {
        const double* Ap = (k0 < Keach) ? A1 : A2;
        const float*  Wp = (k0 < Keach) ? W1 : W2;
        const int kbase = (k0 < Keach) ? k0 : k0 - Keach;

        __syncthreads();
        {
            const double* src = &Ap[(size_t)(b0 + ar) * Hdim + kbase + 4 * akq];
            f64x2 v0 = *(const f64x2*)(src);
            f64x2 v1 = *(const f64x2*)(src + 2);
            *(f64x2*)&As[ar][4 * akq]     = v0;
            *(f64x2*)&As[ar][4 * akq + 2] = v1;
        }
        {
            const float* src = &Wp[(size_t)(n0 + bn) * Keach + kbase + 8 * bh];
            f32x4 u0 = *(const f32x4*)(src);
            f32x4 u1 = *(const f32x4*)(src + 4);
            f64x2 d0 = {(double)u0.x, (double)u0.y};
            f64x2 d1 = {(double)u0.z, (double)u0.w};
            f64x2 d2 = {(double)u1.x, (double)u1.y};
            f64x2 d3 = {(double)u1.z, (double)u1.w};
            *(f64x2*)&Bs[bn][8 * bh]     = d0;
            *(f64x2*)&Bs[bn][8 * bh + 2] = d1;
            *(f64x2*)&Bs[bn][8 * bh + 4] = d2;
            *(f64x2*)&Bs[bn][8 * bh + 6] = d3;
        }
        __syncthreads();

#pragma unroll
        for (int kk = 0; kk < 4; kk++) {
            const int kaI = 4 * kk + ka;
            const int kbI = 4 * kk + kb;
            double a0 = As[ra +  0][kaI];
            double a1 = As[ra + 16][kaI];
            double a2 = As[ra + 32][kaI];
            double a3 = As[ra + 48][kaI];
            double bb0 = Bs[32 * w + cb +  0][kbI];
            double bb1 = Bs[32 * w + cb + 16][kbI];
            acc[0][0] = __builtin_amdgcn_mfma_f64_16x16x4f64(a0, bb0, acc[0][0], 0, 0, 0);
            acc[1][0] = __builtin_amdgcn_mfma_f64_16x16x4f64(a1, bb0, acc[1][0], 0, 0, 0);
            acc[2][0] = __builtin_amdgcn_mfma_f64_16x16x4f64(a2, bb0, acc[2][0], 0, 0, 0);
            acc[3][0] = __builtin_amdgcn_mfma_f64_16x16x4f64(a3, bb0, acc[3][0], 0, 0, 0);
            acc[0][1] = __builtin_amdgcn_mfma_f64_16x16x4f64(a0, bb1, acc[0][1], 0, 0, 0);
            acc[1][1] = __builtin_amdgcn_mfma_f64_16x16x4f64(a1, bb1, acc[1][1], 0, 0, 0);
            acc[2][1] = __builtin_amdgcn_mfma_f64_16x16x4f64(a2, bb1, acc[2][1], 0, 0, 0);
            acc[3][1] = __builtin_amdgcn_mfma_f64_16x16x4f64(a3, bb1, acc[3][1], 0, 0, 0);
        }
    }

#pragma unroll
    for (int fi = 0; fi < 4; fi++) {
#pragma unroll
        for (int fj = 0; fj < 2; fj++) {
#pragma unroll
            for (int r = 0; r < 4; r++) {
                int row = b0 + 16 * fi + (int)((pd >> (4 * r)) & 15u);
                int col = n0 + 32 * w + 16 * fj + (int)((pd >> (16 + 4 * r)) & 15u);
                C[(size_t)row * G4dim + col] = acc[fi][fj][r] + (double)b1[col] + (double)b2[col];
            }
        }
    }
}

// ======== i8 Ozaki-split GEMM (3-digit, 6 products s<=2), K-chunk 32, ring-4 ========
// h = Xh*2^-22, w = Xw*2^-25 (3 signed int8 digits each, MSB first). Diagonals s=i+j<=2
// kept (6 MFMAs/chunk/cf-slice); i32 accumulation exact. gate scale(s) = 2^(-15-8s).
// W packed gate-interleaved pc=4j+g: [panel][chunk32][d(3)][ks(2)][col(192)][16B].
// A packed [d(3)][slot=k/16][b][16B] (single buffer; kernel serialization = WAR safety).
// Tile 128x192, 8 waves, grid 256 = 1/CU, K-chunk 32, ring-4 LDS (4x30720B = 120KB).
// DEPTH-3 counted prefetch: prologue stages chunks 0,1,2; iter c stages c+3.
// [wait vmcnt(8/6) (chunk-c done; c+1,c+2 in flight)] [barrier] [STAGE(c+3)] [compute(c)].
// WAR: barrier at iter-c start orders iter-(c-1) reads before buf[(c+3)&3]=buf[(c-1)&3] reuse.
__global__ __launch_bounds__(512, 2)
void gemm_i8_kernel(const int8_t* __restrict__ Apack, const int8_t* __restrict__ Wpack,
                    const double* __restrict__ bsum, float* __restrict__ Gout, int K) {
    __shared__ int8_t lds8[122880];   // ring: 4 x 30720
    const int tid  = threadIdx.x;
    const int lane = tid & 63;
    const int w    = tid >> 6;

    const int orig = (int)blockIdx.x;
    const int wgid = (orig & 7) * 32 + (orig >> 3);   // XCD-bijective (256 = 32*8)
    const int b0 = (wgid & 7) * 128;
    const int panel = wgid >> 3;              // 0..31
    const int n0 = panel * 192;

    const int wr = w & 3;
    const int wc = w >> 2;
    const int lm = lane & 31;
    const int lh = lane >> 5;

    const int nc = K >> 5;                    // 48 (L0) or 96 (L1)
    const int8_t* Wp = Wpack + (size_t)panel * nc * 18432;

    i32x16 acc[3][3];
#pragma unroll
    for (int cf = 0; cf < 3; cf++)
#pragma unroll
        for (int s = 0; s < 3; s++)
            acc[cf][s] = (i32x16){0,0,0,0,0,0,0,0,0,0,0,0,0,0,0,0};

    auto STAGE = [&](int8_t* buf, int c) {
#pragma unroll
        for (int u = 0; u < 4; u++) {
            const int li = 8 * u + w;         // 0..31
            if (li >= 30) continue;           // waves 6,7 issue 3; waves 0-5 issue 4
            if (li < 12) {
                const int d = li >> 2, ks = (li >> 1) & 1, hf = li & 1;
                const int8_t* src = Apack + (size_t)d * APL3
                                  + (((size_t)(c * 2 + ks)) * 1024 + b0 + hf * 64 + lane) * 16;
                gload_lds16(src, buf + ((d * 2 + ks) * 128 + hf * 64) * 16);
            } else {
                const int bli = li - 12;      // 0..17
                const int d = bli / 6, rem = bli % 6, ks = rem / 3, th = rem % 3;
                const int8_t* src = Wp + (size_t)c * 18432
                                  + ((d * 2 + ks) * 192 + th * 64 + lane) * 16;
                gload_lds16(src, buf + 12288 + ((d * 2 + ks) * 192 + th * 64) * 16);
            }
        }
    };

    STAGE(lds8, 0);
    STAGE(lds8 + 30720, 1);
    STAGE(lds8 + 61440, 2);

    for (int c = 0; c < nc; c++) {
        // staged-through chunk min(nc-1, c+2); wait until chunk-c loads complete
        if (c + 3 <= nc) {                    // chunks c+1, c+2 still in flight
            if (w < 6) asm volatile("s_waitcnt vmcnt(8)" ::: "memory");
            else       asm volatile("s_waitcnt vmcnt(6)" ::: "memory");
        } else if (c + 2 == nc) {             // only chunk c+1 in flight
            if (w < 6) asm volatile("s_waitcnt vmcnt(4)" ::: "memory");
            else       asm volatile("s_waitcnt vmcnt(3)" ::: "memory");
        } else {
            asm volatile("s_waitcnt vmcnt(0)" ::: "memory");
        }
        __builtin_amdgcn_s_barrier();         // all waves: chunk-c in LDS; reads of c-1 done
        if (c + 3 < nc) STAGE(lds8 + ((c + 3) & 3) * 30720, c + 3);

        const int8_t* buf = lds8 + (c & 3) * 30720;
        i32x4 a0 = *(const i32x4*)(buf + ((0 * 2 + lh) * 128 + wr * 32 + lm) * 16);
        i32x4 a1 = *(const i32x4*)(buf + ((1 * 2 + lh) * 128 + wr * 32 + lm) * 16);
        i32x4 a2 = *(const i32x4*)(buf + ((2 * 2 + lh) * 128 + wr * 32 + lm) * 16);

        __builtin_amdgcn_s_setprio(1);
#pragma unroll
        for (int cf = 0; cf < 3; cf++) {
            const int bcol = wc * 96 + cf * 32 + lm;
            i32x4 b0v = *(const i32x4*)(buf + 12288 + ((0 * 2 + lh) * 192 + bcol) * 16);
            acc[cf][0] = __builtin_amdgcn_mfma_i32_32x32x32_i8(a0, b0v, acc[cf][0], 0, 0, 0);
            acc[cf][1] = __builtin_amdgcn_mfma_i32_32x32x32_i8(a1, b0v, acc[cf][1], 0, 0, 0);
            acc[cf][2] = __builtin_amdgcn_mfma_i32_32x32x32_i8(a2, b0v, acc[cf][2], 0, 0, 0);
            i32x4 b1v = *(const i32x4*)(buf + 12288 + ((1 * 2 + lh) * 192 + bcol) * 16);
            acc[cf][1] = __builtin_amdgcn_mfma_i32_32x32x32_i8(a0, b1v, acc[cf][1], 0, 0, 0);
            acc[cf][2] = __builtin_amdgcn_mfma_i32_32x32x32_i8(a1, b1v, acc[cf][2], 0, 0, 0);
            i32x4 b2v = *(const i32x4*)(buf + 12288 + ((2 * 2 + lh) * 192 + bcol) * 16);
            acc[cf][2] = __builtin_amdgcn_mfma_i32_32x32x32_i8(a0, b2v, acc[cf][2], 0, 0, 0);
        }
        __builtin_amdgcn_s_setprio(0);
    }

    // epilogue: C/D 32x32 layout (col=lane&31, row=(r&3)+8*(r>>2)+4*(lane>>5));
    // per (cf,r): 32 lanes write 32 consecutive f32 -> 128B coalesced stores.
#pragma unroll
    for (int cf = 0; cf < 3; cf++) {
        const int pc = n0 + wc * 96 + cf * 32 + lm;
        const double bb = bsum[pc];
#pragma unroll
        for (int r = 0; r < 16; r++) {
            const int row = b0 + wr * 32 + (r & 3) + 8 * (r >> 2) + 4 * lh;
            Gout[(size_t)row * G4dim + pc] = (float)(
                  (double)acc[cf][0][r] * 0x1p-15
                + (double)acc[cf][1][r] * 0x1p-23
                + (double)acc[cf][2][r] * 0x1p-31 + bb);
        }
    }
}

// ---------------- LSTM cell (i8 path): f32 gates, f32 c state, f32 transcendentals ----
__global__ __launch_bounds__(256)
void cell_i8_kernel(const float* __restrict__ G, float* __restrict__ c,
                    const float* __restrict__ Wg, const int* __restrict__ idx,
                    int useGather, int8_t* __restrict__ Apack, int koff) {
    int e = blockIdx.x * 256 + threadIdx.x;     // 0 .. B*H-1
    int b = e / Hdim, j = e - b * Hdim;
    const f32x4 gv = *(const f32x4*)(G + (size_t)b * G4dim + 4 * j);
    float gi = gv.x, gf = gv.y, gg = gv.z, go = gv.w;
    if (useGather) {
        const f32x4 wv = *(const f32x4*)(Wg + (size_t)idx[b] * G4dim + 4 * j);
        gi += wv.x; gf += wv.y; gg += wv.z; go += wv.w;
    }
    float si = 1.0f / (1.0f + expf(-gi));
    float sf = 1.0f / (1.0f + expf(-gf));
    float tg = tanhf(gg);
    float so = 1.0f / (1.0f + expf(-go));
    float cn = sf * c[e] + si * tg;
    c[e] = cn;
    float hn = so * tanhf(cn);
    int X = __float2int_rn(hn * 4194304.0f);    // h * 2^22, |h| <= 1
    int8_t q0, q1, q2;
    digits3(X, q0, q1, q2);
    const int slot = (koff + j) >> 4, byte = j & 15;
    const size_t ab = ((size_t)slot * 1024 + b) * 16 + byte;
    Apack[ab]            = q0;
    Apack[APL3 + ab]     = q1;
    Apack[2 * APL3 + ab] = q2;
}

// ======== i8 logits GEMM (3-digit, 6 products, packed): Lpart[ksp][b][v] (f32) ========
__global__ __launch_bounds__(256)
void logits_i8_kernel(const int8_t* __restrict__ Apack, const int8_t* __restrict__ Wodp,
                      float* __restrict__ Lpart) {
    __shared__ int8_t lds8[24576];
    const int tid  = threadIdx.x;
    const int lane = tid & 63;
    const int w    = tid >> 6;
    const int b0   = blockIdx.x * 64;
    const int p    = blockIdx.y;
    const int ksp  = blockIdx.z;

    const int rh = w & 1;
    const int cw = w >> 1;
    const int lm = lane & 31;
    const int lh = lane >> 5;

    i32x16 acc[3];
#pragma unroll
    for (int s = 0; s < 3; s++)
        acc[s] = (i32x16){0,0,0,0,0,0,0,0,0,0,0,0,0,0,0,0};

    for (int c = 0; c < 6; c++) {
        __syncthreads();
#pragma unroll
        for (int u = 0; u < 6; u++) {
            const int li = 4 * u + w;     // 0..23
            if (li < 12) {
                const int d = li >> 2, ks = li & 3;
                const int slot = 96 + ksp * 24 + c * 4 + ks;
                const int8_t* src = Apack + (size_t)d * APL3
                                  + ((size_t)slot * 1024 + b0 + lane) * 16;
                gload_lds16(src, lds8 + li * 1024);
            } else {
                const int bli = li - 12;
                const int d = bli >> 2, ks = bli & 3;
                const int seg = ((p * 24 + ksp * 6 + c) * 3 + d) * 4 + ks;
                const int8_t* src = Wodp + ((size_t)seg * 64 + lane) * 16;
                gload_lds16(src, lds8 + 12288 + bli * 1024);
            }
        }
        __syncthreads();

#pragma unroll
        for (int kk = 0; kk < 2; kk++) {
            const int ks = 2 * kk + lh;
            i32x4 a[3], bb[3];
#pragma unroll
            for (int d = 0; d < 3; d++) {
                a[d]  = *(const i32x4*)(lds8 + ((d * 4 + ks) * 64 + rh * 32 + lm) * 16);
                bb[d] = *(const i32x4*)(lds8 + 12288 + ((d * 4 + ks) * 64 + cw * 32 + lm) * 16);
            }
            acc[0] = __builtin_amdgcn_mfma_i32_32x32x32_i8(a[0], bb[0], acc[0], 0, 0, 0);
            acc[1] = __builtin_amdgcn_mfma_i32_32x32x32_i8(a[0], bb[1], acc[1], 0, 0, 0);
            acc[1] = __builtin_amdgcn_mfma_i32_32x32x32_i8(a[1], bb[0], acc[1], 0, 0, 0);
            acc[2] = __builtin_amdgcn_mfma_i32_32x32x32_i8(a[0], bb[2], acc[2], 0, 0, 0);
            acc[2] = __builtin_amdgcn_mfma_i32_32x32x32_i8(a[1], bb[1], acc[2], 0, 0, 0);
            acc[2] = __builtin_amdgcn_mfma_i32_32x32x32_i8(a[2], bb[0], acc[2], 0, 0, 0);
        }
    }

    const int col = p * 64 + cw * 32 + lm;
#pragma unroll
    for (int r = 0; r < 16; r++) {
        const int row = b0 + rh * 32 + (r & 3) + 8 * (r >> 2) + 4 * lh;
        const double g = (double)acc[0][r] * 0x1p-15
                       + (double)acc[1][r] * 0x1p-23
                       + (double)acc[2][r] * 0x1p-31;
        Lpart[((size_t)ksp * Bdim + row) * Vdim + col] = (float)g;
    }
}

// ---- gate-W 3-digit quantization, gate-interleaved packed (pc = 4j+g), chunk32 ----
__global__ __launch_bounds__(256)
void wquant_gate_kernel(const float* __restrict__ W, int8_t* __restrict__ out,
                        int col0, int NCH, int total4) {
    int t = blockIdx.x * 256 + threadIdx.x;
    if (t >= total4) return;
    int n = (4 * t) / Hdim, k = (4 * t) % Hdim;
    f32x4 wv = *(const f32x4*)(W + (size_t)n * Hdim + k);
    uint32_t pk[3] = {0, 0, 0};
#pragma unroll
    for (int l = 0; l < 4; l++) {
        double x = (double)wv[l] * 33554432.0;     // w * 2^25
        x = fmin(fmax(x, -8323072.0), 8323072.0);
        int X = __double2int_rn(x);
        int8_t e0, e1, e2;
        digits3(X, e0, e1, e2);
        pk[0] |= ((uint32_t)(uint8_t)e0) << (8 * l);
        pk[1] |= ((uint32_t)(uint8_t)e1) << (8 * l);
        pk[2] |= ((uint32_t)(uint8_t)e2) << (8 * l);
    }
    const int pcol = 4 * (n % 1536) + n / 1536;
    const int p = pcol / 192, col = pcol % 192;
    const int kk = col0 + k;
    const int c = kk >> 5, ks = (kk >> 4) & 1, byte = kk & 15;
#pragma unroll
    for (int d = 0; d < 3; d++) {
        size_t off = ((size_t)(p * NCH + c) * 6 + d * 2 + ks) * 3072 + col * 16 + byte;
        *(uint32_t*)(out + off) = pk[d];
    }
}

// ---- W_out 3-digit quantization into packed layout ----
__global__ __launch_bounds__(256)
void wquant_out_kernel(const float* __restrict__ W, int8_t* __restrict__ out, int total4) {
    int t = blockIdx.x * 256 + threadIdx.x;
    if (t >= total4) return;
    int n = (4 * t) / Hdim, k = (4 * t) % Hdim;
    f32x4 wv = *(const f32x4*)(W + (size_t)n * Hdim + k);
    uint32_t pk[3] = {0, 0, 0};
#pragma unroll
    for (int l = 0; l < 4; l++) {
        double x = (double)wv[l] * 33554432.0;
        x = fmin(fmax(x, -8323072.0), 8323072.0);
        int X = __double2int_rn(x);
        int8_t e0, e1, e2;
        digits3(X, e0, e1, e2);
        pk[0] |= ((uint32_t)(uint8_t)e0) << (8 * l);
        pk[1] |= ((uint32_t)(uint8_t)e1) << (8 * l);
        pk[2] |= ((uint32_t)(uint8_t)e2) << (8 * l);
    }
    const int p = n >> 6, col = n & 63;
    const int c = k >> 6, ks = (k >> 4) & 3, byte = k & 15;
#pragma unroll
    for (int d = 0; d < 3; d++) {
        size_t off = ((size_t)((p * 24 + c) * 3 + d) * 4 + ks) * 1024 + col * 16 + byte;
        *(uint32_t*)(out + off) = pk[d];
    }
}

// ---- bias pack: bs[4*j+g] = b1[g*H+j] + b2[g*H+j] ----
__global__ __launch_bounds__(256)
void biaspack_kernel(const float* __restrict__ b1, const float* __restrict__ b2,
                     double* __restrict__ bs) {
    int n = blockIdx.x * 256 + threadIdx.x;
    if (n >= G4dim) return;
    int g = n / Hdim, j = n % Hdim;
    bs[4 * j + g] = (double)b1[n] + (double)b2[n];
}

// ---- W_ih0 transpose into packed cols: Wt[v][4*j+g] = W[g*H+j][v] ----
__global__ __launch_bounds__(256)
void wtrans_kernel(const float* __restrict__ W, float* __restrict__ Wt) {
    __shared__ float tile[32][33];
    const int tx = threadIdx.x & 31, ty = threadIdx.x >> 5;
    const int r0 = blockIdx.x * 32;
    const int c0 = blockIdx.y * 32;
#pragma unroll
    for (int r = 0; r < 4; r++)
        tile[ty + 8 * r][tx] = W[(size_t)(r0 + ty + 8 * r) * Vdim + c0 + tx];
    __syncthreads();
    const int g = r0 / 1536;
#pragma unroll
    for (int r = 0; r < 4; r++) {
        const int n = r0 + tx;
        const int pc = 4 * (n % 1536) + g;
        Wt[(size_t)(c0 + ty + 8 * r) * G4dim + pc] = tile[tx][ty + 8 * r];
    }
}

// ---------------- LSTM cell pointwise update (fallback path only) ----------------
__global__ __launch_bounds__(256)
void cell_kernel(const double* __restrict__ G, double* __restrict__ c,
                 double* __restrict__ hout, const float* __restrict__ Wx,
                 const int* __restrict__ idx, int useGather) {
    int e = blockIdx.x * 256 + threadIdx.x;
    int b = e / Hdim, j = e - b * Hdim;
    size_t gb = (size_t)b * G4dim;
    double gi = G[gb + j];
    double gf = G[gb + Hdim + j];
    double gg = G[gb + 2 * Hdim + j];
    double go = G[gb + 3 * Hdim + j];
    if (useGather) {
        int id = idx[b];
        gi += (double)Wx[(size_t)(0 * Hdim + j) * Vdim + id];
        gf += (double)Wx[(size_t)(1 * Hdim + j) * Vdim + id];
        gg += (double)Wx[(size_t)(2 * Hdim + j) * Vdim + id];
        go += (double)Wx[(size_t)(3 * Hdim + j) * Vdim + id];
    }
    double si = 1.0 / (1.0 + exp(-gi));
    double sf = 1.0 / (1.0 + exp(-gf));
    double tg = tanh(gg);
    double so = 1.0 / (1.0 + exp(-go));
    double cn = sf * c[e] + si * tg;
    c[e] = cn;
    hout[e] = so * tanh(cn);
}

// ---- f64 vector GEMM (fallback noise t=0, plain cols) ----
__global__ __launch_bounds__(256)
void gemm_kernel(const float* __restrict__ A, const float* __restrict__ W,
                 double* __restrict__ C, int K) {
    __shared__ double As[16][65];
    __shared__ float  Wsf[16][68];
    const int tid = threadIdx.x;
    const int b0 = blockIdx.x * 64;
    const int n0 = blockIdx.y * 64;
    const int tm = tid >> 4;
    const int tn = tid & 15;

    double acc[4][4];
#pragma unroll
    for (int i = 0; i < 4; i++)
#pragma unroll
        for (int j = 0; j < 4; j++) acc[i][j] = 0.0;

    for (int k0 = 0; k0 < K; k0 += 16) {
        __syncthreads();
#pragma unroll
        for (int l = 0; l < 4; l++) {
            int e = tid + l * 256;
            int i = e >> 4, k = e & 15;
            As[k][i] = (double)A[(size_t)(b0 + i) * K + k0 + k];
            Wsf[k][i] = W[(size_t)(n0 + i) * K + k0 + k];
        }
        __syncthreads();
#pragma unroll
        for (int k = 0; k < 16; k++) {
            double a0 = As[k][tm * 4 + 0];
            double a1 = As[k][tm * 4 + 1];
            double a2 = As[k][tm * 4 + 2];
            double a3 = As[k][tm * 4 + 3];
            double w0 = (double)Wsf[k][tn * 4 + 0];
            double w1 = (double)Wsf[k][tn * 4 + 1];
            double w2 = (double)Wsf[k][tn * 4 + 2];
            double w3 = (double)Wsf[k][tn * 4 + 3];
            acc[0][0] = fma(a0, w0, acc[0][0]); acc[0][1] = fma(a0, w1, acc[0][1]);
            acc[0][2] = fma(a0, w2, acc[0][2]); acc[0][3] = fma(a0, w3, acc[0][3]);
            acc[1][0] = fma(a1, w0, acc[1][0]); acc[1][1] = fma(a1, w1, acc[1][1]);
            acc[1][2] = fma(a1, w2, acc[1][2]); acc[1][3] = fma(a1, w3, acc[1][3]);
            acc[2][0] = fma(a2, w0, acc[2][0]); acc[2][1] = fma(a2, w1, acc[2][1]);
            acc[2][2] = fma(a2, w2, acc[2][2]); acc[2][3] = fma(a2, w3, acc[2][3]);
            acc[3][0] = fma(a3, w0, acc[3][0]); acc[3][1] = fma(a3, w1, acc[3][1]);
            acc[3][2] = fma(a3, w2, acc[3][2]); acc[3][3] = fma(a3, w3, acc[3][3]);
        }
    }

#pragma unroll
    for (int i = 0; i < 4; i++) {
        int row = b0 + tm * 4 + i;
#pragma unroll
        for (int j = 0; j < 4; j++) {
            int col = n0 + tn * 4 + j;
            C[(size_t)row * G4dim + col] += acc[i][j];
        }
    }
}

// ---- f32 noise GEMM (i8 path, t=0): G[row][4j+g] += noise @ W_ih0^T ----
__global__ __launch_bounds__(256)
void gemm_noise_f32(const float* __restrict__ A, const float* __restrict__ W,
                    float* __restrict__ C, int K) {
    __shared__ double As[16][65];
    __shared__ float  Wsf[16][68];
    const int tid = threadIdx.x;
    const int b0 = blockIdx.x * 64;
    const int n0 = blockIdx.y * 64;
    const int tm = tid >> 4;
    const int tn = tid & 15;

    double acc[4][4];
#pragma unroll
    for (int i = 0; i < 4; i++)
#pragma unroll
        for (int j = 0; j < 4; j++) acc[i][j] = 0.0;

    for (int k0 = 0; k0 < K; k0 += 16) {
        __syncthreads();
#pragma unroll
        for (int l = 0; l < 4; l++) {
            int e = tid + l * 256;
            int i = e >> 4, k = e & 15;
            As[k][i] = (double)A[(size_t)(b0 + i) * K + k0 + k];
            Wsf[k][i] = W[(size_t)(n0 + i) * K + k0 + k];
        }
        __syncthreads();
#pragma unroll
        for (int k = 0; k < 16; k++) {
            double a0 = As[k][tm * 4 + 0];
            double a1 = As[k][tm * 4 + 1];
            double a2 = As[k][tm * 4 + 2];
            double a3 = As[k][tm * 4 + 3];
            double w0 = (double)Wsf[k][tn * 4 + 0];
            double w1 = (double)Wsf[k][tn * 4 + 1];
            double w2 = (double)Wsf[k][tn * 4 + 2];
            double w3 = (double)Wsf[k][tn * 4 + 3];
            acc[0][0] = fma(a0, w0, acc[0][0]); acc[0][1] = fma(a0, w1, acc[0][1]);
            acc[0][2] = fma(a0, w2, acc[0][2]); acc[0][3] = fma(a0, w3, acc[0][3]);
            acc[1][0] = fma(a1, w0, acc[1][0]); acc[1][1] = fma(a1, w1, acc[1][1]);
            acc[1][2] = fma(a1, w2, acc[1][2]); acc[1][3] = fma(a1, w3, acc[1][3]);
            acc[2][0] = fma(a2, w0, acc[2][0]); acc[2][1] = fma(a2, w1, acc[2][1]);
            acc[2][2] = fma(a2, w2, acc[2][2]); acc[2][3] = fma(a2, w3, acc[2][3]);
            acc[3][0] = fma(a3, w0, acc[3][0]); acc[3][1] = fma(a3, w1, acc[3][1]);
            acc[3][2] = fma(a3, w2, acc[3][2]); acc[3][3] = fma(a3, w3, acc[3][3]);
        }
    }

#pragma unroll
    for (int i = 0; i < 4; i++) {
        int row = b0 + tm * 4 + i;
#pragma unroll
        for (int j = 0; j < 4; j++) {
            int col = n0 + tn * 4 + j;
            int oc = 4 * (col % 1536) + col / 1536;
            C[(size_t)row * G4dim + oc] += (float)acc[i][j];
        }
    }
}

// -- light sampler: sum split-K partials (f32) + bias + gumbel + argmax --
__global__ __launch_bounds__(256)
void sample_lite_kernel(const float* __restrict__ Lpart, const float* __restrict__ bout,
                        const int* __restrict__ seqlen, int* __restrict__ idx,
                        int* __restrict__ out, int t) {
    __shared__ double rz[256];
    __shared__ int    rv[256];
    const int b = blockIdx.x;
    const int v = threadIdx.x;
    const size_t o = (size_t)b * Vdim + v;
    const size_t P = (size_t)Bdim * Vdim;

    double z = (double)Lpart[o] + (double)Lpart[P + o] + (double)Lpart[2 * P + o]
             + (double)Lpart[3 * P + o] + (double)bout[v];

    uint32_t kt0, kt1;
    tf2x32(0u, 42u, 0u, (uint32_t)t, kt0, kt1);
    uint32_t m = (uint32_t)(b * Vdim + v);
    uint32_t o0, o1;
    tf2x32(kt0, kt1, 0u, m, o0, o1);
    uint32_t bits = o0 ^ o1;
    float f = __uint_as_float((bits >> 9) | 0x3f800000u) - 1.0f;
    double u = (f > 0.f) ? (double)f : (double)1.1754943508222875e-38f;
    float gum32 = (float)(-log(-log(u)));
    z += (double)gum32;

    rz[v] = z; rv[v] = v;
    __syncthreads();
    for (int s = 128; s > 0; s >>= 1) {
        if (v < s) {
            double zo = rz[v + s]; int vo = rv[v + s];
            if (zo > rz[v] || (zo == rz[v] && vo < rv[v])) { rz[v] = zo; rv[v] = vo; }
        }
        __syncthreads();
    }
    if (v == 0) {
        int wv = rv[0];
        idx[b] = wv;
        out[(size_t)t * Bdim + b] = (t < seqlen[b]) ? wv : 0;
    }
}

// -- f64-path sampler (fallback) --
__global__ __launch_bounds__(256)
void sample_kernel(const double* __restrict__ h1, const float* __restrict__ Wout,
                   const float* __restrict__ bout, const int* __restrict__ seqlen,
                   int* __restrict__ idx, int* __restrict__ out, int t) {
    __shared__ double hs[Hdim];
    __shared__ float  Ws[256][33];
    __shared__ double rz[256];
    __shared__ int    rv[256];
    const int b = blockIdx.x;
    const int v = threadIdx.x;

    for (int k = v; k < Hdim; k += 256) hs[k] = h1[(size_t)b * Hdim + k];

    double acc = 0.0;
    for (int kc = 0; kc < Hdim; kc += 32) {
        __syncthreads();
#pragma unroll
        for (int l = 0; l < 32; l++) {
            int e = v + l * 256;
            int vv = e >> 5, kk = e & 31;
            Ws[vv][kk] = Wout[(size_t)vv * Hdim + kc + kk];
        }
        __syncthreads();
#pragma unroll
        for (int kk = 0; kk < 32; kk++)
            acc = fma((double)Ws[v][kk], hs[kc + kk], acc);
    }

    double z = acc + (double)bout[v];

    uint32_t kt0, kt1;
    tf2x32(0u, 42u, 0u, (uint32_t)t, kt0, kt1);
    uint32_t m = (uint32_t)(b * Vdim + v);
    uint32_t o0, o1;
    tf2x32(kt0, kt1, 0u, m, o0, o1);
    uint32_t bits = o0 ^ o1;
    float f = __uint_as_float((bits >> 9) | 0x3f800000u) - 1.0f;
    double u = (f > 0.f) ? (double)f : (double)1.1754943508222875e-38f;
    float gum32 = (float)(-log(-log(u)));
    z += (double)gum32;

    rz[v] = z; rv[v] = v;
    __syncthreads();
    for (int s = 128; s > 0; s >>= 1) {
        if (v < s) {
            double zo = rz[v + s]; int vo = rv[v + s];
            if (zo > rz[v] || (zo == rz[v] && vo < rv[v])) { rz[v] = zo; rv[v] = vo; }
        }
        __syncthreads();
    }
    if (v == 0) {
        int wv = rv[0];
        idx[b] = wv;
        out[(size_t)t * Bdim + b] = (t < seqlen[b]) ? wv : 0;
    }
}

// ---------------- diagnostic sentinel ----------------
__global__ void sentinel_kernel(int* out, int n, int val) {
    int i = blockIdx.x * 256 + threadIdx.x;
    if (i < n) out[i] = val;
}

// ---------------- host orchestration ----------------
extern "C" void kernel_launch(void* const* d_in, const int* in_sizes, int n_in,
                              void* d_out, int out_size, void* d_ws, size_t ws_size,
                              hipStream_t stream) {
    int* out = (int*)d_out;

    const size_t base_dbl = ((size_t)Bdim * G4dim + 4ull * Bdim * Hdim) * sizeof(double);
    const size_t misc = 8192;
    const size_t needed_f64 = base_dbl + misc;
    const size_t apk_sz   = 3ull * APL3;                         // 9.4 MB
    const size_t wd0_sz   = 3ull * G4dim * Hdim;                 // 28.3 MB
    const size_t wd1_sz   = 3ull * G4dim * (2 * Hdim);           // 56.6 MB
    const size_t wod_sz   = 3ull * Vdim * Hdim;                  // 1.18 MB
    const size_t lpart_sz = 4ull * Bdim * Vdim * sizeof(double); // 8.4 MB (f32 uses half)
    const size_t wt_sz    = (size_t)Vdim * G4dim * sizeof(float);// 6.3 MB
    const size_t bs_sz    = (size_t)G4dim * sizeof(double);
    const size_t needed_i8 = needed_f64 + apk_sz + wd0_sz + wd1_sz + wod_sz
                           + lpart_sz + wt_sz + 2 * bs_sz;

    if (ws_size < needed_f64) {
        sentinel_kernel<<<(out_size + 255) / 256, 256, 0, stream>>>(out, out_size, 1000000);
        return;
    }
    const int expect[12] = {Bdim * Vdim, Bdim, G4dim * Vdim, G4dim * Hdim, G4dim, G4dim,
                            G4dim * Hdim, G4dim * Hdim, G4dim, G4dim, Vdim * Hdim, Vdim};
    bool ok = (n_in == 12);
    for (int i = 0; ok && i < 12; i++) ok = (in_sizes[i] == expect[i]);
    if (!ok) {
        sentinel_kernel<<<(out_size + 255) / 256, 256, 0, stream>>>(out, out_size, 2000000);
        return;
    }

    const float* noise  = (const float*)d_in[0];
    const int*   seqlen = (const int*)d_in[1];
    const float* W_ih0  = (const float*)d_in[2];
    const float* W_hh0  = (const float*)d_in[3];
    const float* b_ih0  = (const float*)d_in[4];
    const float* b_hh0  = (const float*)d_in[5];
    const float* W_ih1  = (const float*)d_in[6];
    const float* W_hh1  = (const float*)d_in[7];
    const float* b_ih1  = (const float*)d_in[8];
    const float* b_hh1  = (const float*)d_in[9];
    const float* W_out  = (const float*)d_in[10];
    const float* b_out  = (const float*)d_in[11];

    double* G  = (double*)d_ws;
    double* h0 = G  + (size_t)Bdim * G4dim;
    double* c0 = h0 + (size_t)Bdim * Hdim;
    double* h1 = c0 + (size_t)Bdim * Hdim;
    double* c1 = h1 + (size_t)Bdim * Hdim;
    int*   idx = (int*)(c1 + (size_t)Bdim * Hdim);
    int*  lutAB = idx + Bdim;
    uint32_t* lutD = (uint32_t*)(lutAB + 64);
    int8_t* Apack = (int8_t*)(lutD + 64);
    int8_t* Wd0  = Apack + apk_sz;
    int8_t* Wd1  = Wd0 + wd0_sz;
    int8_t* Wod  = Wd1 + wd1_sz;
    double* Lpart = (double*)(Wod + wod_sz);
    float*  Wih0t = (float*)(Lpart + 4ull * Bdim * Vdim);
    double* bs0  = (double*)(Wih0t + (size_t)Vdim * G4dim);
    double* bs1  = bs0 + G4dim;

    float* Gf = (float*)G;              // i8 path uses G region as f32
    float* Lpf = (float*)Lpart;         // i8 path uses Lpart region as f32
    float* cf0 = (float*)c0;            // i8 path: f32 c state (region zeroed below)
    float* cf1 = (float*)c1;

    const bool use_i8 = (ws_size >= needed_i8);

    (void)hipMemsetAsync(h0, 0, (size_t)4 * Bdim * Hdim * sizeof(double), stream);

    dim3 gOld(Bdim / 64, G4dim / 64);

    if (use_i8) {
        (void)hipMemsetAsync(Apack, 0, apk_sz, stream);
        const int nq = G4dim * Hdim / 4;
        wquant_gate_kernel<<<(nq + 255) / 256, 256, 0, stream>>>(W_hh0, Wd0, 0, 48, nq);
        wquant_gate_kernel<<<(nq + 255) / 256, 256, 0, stream>>>(W_ih1, Wd1, 0, 96, nq);
        wquant_gate_kernel<<<(nq + 255) / 256, 256, 0, stream>>>(W_hh1, Wd1, Hdim, 96, nq);
        const int nqo = Vdim * Hdim / 4;
        wquant_out_kernel<<<(nqo + 255) / 256, 256, 0, stream>>>(W_out, Wod, nqo);
        wtrans_kernel<<<dim3(G4dim / 32, Vdim / 32), 256, 0, stream>>>(W_ih0, Wih0t);
        biaspack_kernel<<<G4dim / 256, 256, 0, stream>>>(b_ih0, b_hh0, bs0);
        biaspack_kernel<<<G4dim / 256, 256, 0, stream>>>(b_ih1, b_hh1, bs1);

        for (int t = 0; t < Tdim; t++) {
            // L0 gates: Gf[row][4j+g] = h0_old @ W_hh0^T + bias (f32, packed cols)
            gemm_i8_kernel<<<256, 512, 0, stream>>>(Apack, Wd0, bs0, Gf, Hdim);
            if (t == 0)   // x = noise: f64-acc GEMM adds into packed f32 G, once
                gemm_noise_f32<<<gOld, 256, 0, stream>>>(noise, W_ih0, Gf, Vdim);
            // cell L0: f32 gates + gather + f32 activations; writes h0 digits (slots 0..95)
            cell_i8_kernel<<<Bdim * Hdim / 256, 256, 0, stream>>>(Gf, cf0, Wih0t, idx,
                                                                  t > 0 ? 1 : 0, Apack, 0);
            // L1 gates: h0_new (slots 0..95) | h1_old (slots 96..191), K=3072 merged
            gemm_i8_kernel<<<256, 512, 0, stream>>>(Apack, Wd1, bs1, Gf, 2 * Hdim);
            // cell L1: writes h1 digits (slots 96..191)
            cell_i8_kernel<<<Bdim * Hdim / 256, 256, 0, stream>>>(Gf, cf1, nullptr, nullptr,
                                                                  0, Apack, Hdim);
            // logits via i8 split-K GEMM (f32 partials), then light sampler
            logits_i8_kernel<<<dim3(16, 4, 4), 256, 0, stream>>>(Apack, Wod, Lpf);
            sample_lite_kernel<<<Bdim, 256, 0, stream>>>(Lpf, b_out, seqlen, idx, out, t);
        }
    } else {
        mfma_probe_kernel<<<1, 64, 0, stream>>>(lutAB, lutD);
        dim3 gM(Bdim / 64, G4dim / 128);
        for (int t = 0; t < Tdim; t++) {
            gemm_mfma_kernel<<<gM, 256, 0, stream>>>(h0, h0, W_hh0, W_hh0, G, b_ih0, b_hh0,
                                                     lutAB, lutD, Hdim, 1);
            if (t == 0)
                gemm_kernel<<<gOld, 256, 0, stream>>>(noise, W_ih0, G, Vdim);
            cell_kernel<<<Bdim * Hdim / 256, 256, 0, stream>>>(G, c0, h0, W_ih0, idx,
                                                               t > 0 ? 1 : 0);
            gemm_mfma_kernel<<<gM, 256, 0, stream>>>(h0, h1, W_ih1, W_hh1, G, b_ih1, b_hh1,
                                                     lutAB, lutD, Hdim, 2);
            cell_kernel<<<Bdim * Hdim / 256, 256, 0, stream>>>(G, c1, h1, nullptr, nullptr, 0);
            sample_kernel<<<Bdim, 256, 0, stream>>>(h1, W_out, b_out, seqlen, idx, out, t);
        }
    }
}

// Round 14
// 48953.607 us; speedup vs baseline: 1.6200x; 1.0180x over previous
//
#include <hip/hip_runtime.h>
#include <stdint.h>
#include <math.h>
#include <string.h>

#define Bdim 1024
#define Vdim 256
#define Hdim 1536
#define G4dim 6144
#define Tdim 256
// packed A digits: [d][slot=k/16 (192)][b (1024)][16B]; per-plane bytes (3 planes):
#define APL3 ((size_t)192 * 1024 * 16)

typedef double f64x2 __attribute__((ext_vector_type(2)));
typedef double f64x4 __attribute__((ext_vector_type(4)));
typedef float  f32x4 __attribute__((ext_vector_type(4)));
typedef int    i32x4  __attribute__((ext_vector_type(4)));
typedef int    i32x16 __attribute__((ext_vector_type(16)));

// ---------------- threefry2x32 (JAX default PRNG) ----------------
__device__ __forceinline__ uint32_t rotl32(uint32_t x, uint32_t r) {
    return (x << r) | (x >> (32u - r));
}

__device__ __forceinline__ void tf2x32(uint32_t k0, uint32_t k1, uint32_t x0, uint32_t x1,
                                       uint32_t &o0, uint32_t &o1) {
    uint32_t k2 = k0 ^ k1 ^ 0x1BD11BDAu;
    x0 += k0; x1 += k1;
    x0 += x1; x1 = rotl32(x1, 13); x1 ^= x0;
    x0 += x1; x1 = rotl32(x1, 15); x1 ^= x0;
    x0 += x1; x1 = rotl32(x1, 26); x1 ^= x0;
    x0 += x1; x1 = rotl32(x1, 6);  x1 ^= x0;
    x0 += k1; x1 += k2 + 1u;
    x0 += x1; x1 = rotl32(x1, 17); x1 ^= x0;
    x0 += x1; x1 = rotl32(x1, 29); x1 ^= x0;
    x0 += x1; x1 = rotl32(x1, 16); x1 ^= x0;
    x0 += x1; x1 = rotl32(x1, 24); x1 ^= x0;
    x0 += k2; x1 += k0 + 2u;
    x0 += x1; x1 = rotl32(x1, 13); x1 ^= x0;
    x0 += x1; x1 = rotl32(x1, 15); x1 ^= x0;
    x0 += x1; x1 = rotl32(x1, 26); x1 ^= x0;
    x0 += x1; x1 = rotl32(x1, 6);  x1 ^= x0;
    x0 += k0; x1 += k1 + 3u;
    x0 += x1; x1 = rotl32(x1, 17); x1 ^= x0;
    x0 += x1; x1 = rotl32(x1, 29); x1 ^= x0;
    x0 += x1; x1 = rotl32(x1, 16); x1 ^= x0;
    x0 += x1; x1 = rotl32(x1, 24); x1 ^= x0;
    x0 += k1; x1 += k2 + 4u;
    x0 += x1; x1 = rotl32(x1, 13); x1 ^= x0;
    x0 += x1; x1 = rotl32(x1, 15); x1 ^= x0;
    x0 += x1; x1 = rotl32(x1, 26); x1 ^= x0;
    x0 += x1; x1 = rotl32(x1, 6);  x1 ^= x0;
    x0 += k2; x1 += k0 + 5u;
    o0 = x0; o1 = x1;
}

// ---------------- global_load_lds helper (16B, wave-uniform LDS dest) ----------------
__device__ __forceinline__ void gload_lds16(const void* gsrc, void* ldst) {
    __builtin_amdgcn_global_load_lds(
        (const __attribute__((address_space(1))) uint32_t*)gsrc,
        (__attribute__((address_space(3))) uint32_t*)(uint32_t)(uintptr_t)ldst,
        16, 0, 0);
}

// -------- signed 8-bit digit split (exact two's-complement with carry) --------
__device__ __forceinline__ void digits3(int X, int8_t &d0, int8_t &d1, int8_t &d2) {
    int r = X;
    d2 = (int8_t)r; r = (r - d2) >> 8;
    d1 = (int8_t)r; r = (r - d1) >> 8;
    d0 = (int8_t)r;
}

// ============ MFMA f64 layout calibration probe (fallback path) ============
__global__ void mfma_probe_kernel(int* lutAB, uint32_t* lutD) {
    __shared__ uint32_t rmask[16][2];
    __shared__ uint32_t cmask[16][2];
    __shared__ double Vrow[16];
    __shared__ double Vcol[16];
    __shared__ int row0_ka[4];
    const int l = threadIdx.x;
    const int g = l >> 4, m = l & 15;
    const f64x4 z = {0.0, 0.0, 0.0, 0.0};
    const double one = 1.0;

    double plo = (l < 32) ? ldexp(1.0, l) : 0.0;
    double phi = (l >= 32) ? ldexp(1.0, l - 32) : 0.0;

    f64x4 d1a = __builtin_amdgcn_mfma_f64_16x16x4f64(plo, one, z, 0, 0, 0);
    f64x4 d1b = __builtin_amdgcn_mfma_f64_16x16x4f64(phi, one, z, 0, 0, 0);
    f64x4 d2a = __builtin_amdgcn_mfma_f64_16x16x4f64(one, plo, z, 0, 0, 0);
    f64x4 d2b = __builtin_amdgcn_mfma_f64_16x16x4f64(one, phi, z, 0, 0, 0);

    bool tau = !(d2a[0] == d2a[1] && d2a[0] == d2a[2] && d2a[0] == d2a[3] &&
                 d2b[0] == d2b[1] && d2b[0] == d2b[2] && d2b[0] == d2b[3]);

    if (!tau) {
        if (m == 0)
            for (int r = 0; r < 4; r++) {
                rmask[4 * g + r][0] = (uint32_t)d1a[r];
                rmask[4 * g + r][1] = (uint32_t)d1b[r];
            }
        if (l < 16) { cmask[m][0] = (uint32_t)d2a[0]; cmask[m][1] = (uint32_t)d2b[0]; }
    } else {
        if (l < 16) { rmask[m][0] = (uint32_t)d1a[0]; rmask[m][1] = (uint32_t)d1b[0]; }
        if (m == 0)
            for (int r = 0; r < 4; r++) {
                cmask[4 * g + r][0] = (uint32_t)d2a[r];
                cmask[4 * g + r][1] = (uint32_t)d2b[r];
            }
    }
    __syncthreads();

    int ra = 0, pa = 0, cb = 0, qb = 0;
    for (int i = 0; i < 16; i++) {
        {
            uint32_t lo = rmask[i][0], hi = rmask[i][1];
            bool in = (l < 32) ? ((lo >> l) & 1u) : ((hi >> (l - 32)) & 1u);
            if (in) {
                ra = i;
                uint32_t blo = (l < 32) ? (lo & ((1u << l) - 1u)) : lo;
                uint32_t bhi = (l < 32) ? 0u : (hi & ((1u << (l - 32)) - 1u));
                pa = __popc(blo) + __popc(bhi);
            }
        }
        {
            uint32_t lo = cmask[i][0], hi = cmask[i][1];
            bool in = (l < 32) ? ((lo >> l) & 1u) : ((hi >> (l - 32)) & 1u);
            if (in) {
                cb = i;
                uint32_t blo = (l < 32) ? (lo & ((1u << l) - 1u)) : lo;
                uint32_t bhi = (l < 32) ? 0u : (hi & ((1u << (l - 32)) - 1u));
                qb = __popc(blo) + __popc(bhi);
            }
        }
    }

    f64x4 d3 = __builtin_amdgcn_mfma_f64_16x16x4f64(ldexp(1.0, 8 * pa), ldexp(1.0, 2 * qb), z, 0, 0, 0);

    if (!tau) {
        if (m == 0) for (int r = 0; r < 4; r++) Vrow[4 * g + r] = d3[r];
        if (l < 16) Vcol[m] = d3[0];
    } else {
        if (l < 16) Vrow[m] = d3[0];
        if (m == 0) for (int r = 0; r < 4; r++) Vcol[4 * g + r] = d3[r];
    }
    __syncthreads();

    if (l == 0) {
        uint32_t V = (uint32_t)Vrow[0];
        while (V) { int e = __ffs(V) - 1; V &= V - 1; row0_ka[e >> 3] = (e & 7) >> 1; }
    }
    __syncthreads();

    int ka = 0, kb = 0;
    {
        uint32_t V = (uint32_t)Vrow[ra];
        while (V) { int e = __ffs(V) - 1; V &= V - 1; if ((e >> 3) == pa) ka = (e & 7) >> 1; }
    }
    if (cb == 0) kb = qb;
    else {
        uint32_t V = (uint32_t)Vcol[cb];
        while (V) { int e = __ffs(V) - 1; V &= V - 1; if (((e & 7) >> 1) == qb) kb = row0_ka[e >> 3]; }
    }

    lutAB[l] = ra | (ka << 8) | (cb << 16) | (kb << 24);
    uint32_t pd = 0;
    if (!tau) for (int r = 0; r < 4; r++) { pd |= (uint32_t)(4 * g + r) << (4 * r); pd |= (uint32_t)m << (16 + 4 * r); }
    else      for (int r = 0; r < 4; r++) { pd |= (uint32_t)m << (4 * r); pd |= (uint32_t)(4 * g + r) << (16 + 4 * r); }
    lutD[l] = pd;
}

// ---- f64 MFMA GEMM (fallback path) ----
#define SA 18
#define SB 18
__global__ __launch_bounds__(256, 2)
void gemm_mfma_kernel(const double* __restrict__ A1, const double* __restrict__ A2,
                      const float* __restrict__ W1, const float* __restrict__ W2,
                      double* __restrict__ C, const float* __restrict__ b1,
                      const float* __restrict__ b2, const int* __restrict__ lutAB,
                      const uint32_t* __restrict__ lutD, int Keach, int nParts) {
    __shared__ double As[64][SA];
    __shared__ double Bs[128][SB];
    const int tid  = threadIdx.x;
    const int lane = tid & 63;
    const int w    = tid >> 6;
    const int b0   = blockIdx.x * 64;
    const int n0   = blockIdx.y * 128;

    const int pk = lutAB[lane];
    const int ra = pk & 255;
    const int ka = (pk >> 8) & 255;
    const int cb = (pk >> 16) & 255;
    const int kb = (pk >> 24) & 255;
    const uint32_t pd = lutD[lane];

    const int ar = tid & 63;
    const int akq = tid >> 6;
    const int bn = tid & 127;
    const int bh = tid >> 7;

    f64x4 acc[4][2];
#pragma unroll
    for (int fi = 0; fi < 4; fi++)
#pragma unroll
        for (int fj = 0; fj < 2; fj++) acc[fi][fj] = (f64x4){0.0, 0.0, 0.0, 0.0};

    const int Ktot = Keach * nParts;
    for (int k0 = 0; k0 < Ktot; k0 += 16) {
        const double* Ap = (k0 < Keach) ? A1 : A2;
        const float*  Wp = (k0 < Keach) ? W1 : W2;
        const int kbase = (k0 < Keach) ? k0 : k0 - Keach;

        __syncthreads();
        {
            const double* src = &Ap[(size_t)(b0 + ar) * Hdim + kbase + 4 * akq];
            f64x2 v0 = *(const f64x2*)(src);
            f64x2 v1 = *(const f64x2*)(src + 2);
            *(f64x2*)&As[ar][4 * akq]     = v0;
            *(f64x2*)&As[ar][4 * akq + 2] = v1;
        }
        {
            const float* src = &Wp[(size_t)(n0 + bn) * Keach + kbase + 8 * bh];
            f32x4 u0 = *(const f32x4*)(src);
            f32x4 u1 = *(const f32x4*)(src + 4);
            f64x2 d0 = {(double)u0.x, (double)u0.y};
            f64x2 d1 = {(double)u0.z, (double)u0.w};
            f64x2 d2 = {(double)u1.x, (double)u1.y};
            f64x2 d3 = {(double)u1.z, (double)u1.w};
            *(f64x2*)&Bs[bn][8 * bh]     = d0;
            *(f64x2*)&Bs[bn][8 * bh + 2] = d1;
            *(f64x2*)&Bs[bn][8 * bh + 4] = d2;
            *(f64x2*)&Bs[bn][8 * bh + 6] = d3;
        }
        __syncthreads();

#pragma unroll
        for (int kk = 0; kk < 4; kk++) {
            const int kaI = 4 * kk + ka;
            const int kbI = 4 * kk + kb;
            double a0 = As[ra +  0][kaI];
            double a1 = As[ra + 16][kaI];
            double a2 = As[ra + 32][kaI];
            double a3 = As[ra + 48][kaI];
            double bb0 = Bs[32 * w + cb +  0][kbI];
            double bb1 = Bs[32 * w + cb + 16][kbI];
            acc[0][0] = __builtin_amdgcn_mfma_f64_16x16x4f64(a0, bb0, acc[0][0], 0, 0, 0);
            acc[1][0] = __builtin_amdgcn_mfma_f64_16x16x4f64(a1, bb0, acc[1][0], 0, 0, 0);
            acc[2][0] = __builtin_amdgcn_mfma_f64_16x16x4f64(a2, bb0, acc[2][0], 0, 0, 0);
            acc[3][0] = __builtin_amdgcn_mfma_f64_16x16x4f64(a3, bb0, acc[3][0], 0, 0, 0);
            acc[0][1] = __builtin_amdgcn_mfma_f64_16x16x4f64(a0, bb1, acc[0][1], 0, 0, 0);
            acc[1][1] = __builtin_amdgcn_mfma_f64_16x16x4f64(a1, bb1, acc[1][1], 0, 0, 0);
            acc[2][1] = __builtin_amdgcn_mfma_f64_16x16x4f64(a2, bb1, acc[2][1], 0, 0, 0);
            acc[3][1] = __builtin_amdgcn_mfma_f64_16x16x4f64(a3, bb1, acc[3][1], 0, 0, 0);
        }
    }

#pragma unroll
    for (int fi = 0; fi < 4; fi++) {
#pragma unroll
        for (int fj = 0; fj < 2; fj++) {
#pragma unroll
            for (int r = 0; r < 4; r++) {
                int row = b0 + 16 * fi + (int)((pd >> (4 * r)) & 15u);
                int col = n0 + 32 * w + 16 * fj + (int)((pd >> (16 + 4 * r)) & 15u);
                C[(size_t)row * G4dim + col] = acc[fi][fj][r] + (double)b1[col] + (double)b2[col];
            }
        }
    }
}

// ======== i8 Ozaki-split GEMM (3-digit, 6 products s<=2), 12 waves, 3 waves/SIMD ======
// h = Xh*2^-22, w = Xw*2^-25 (3 signed int8 digits each, MSB first). Diagonals s=i+j<=2
// kept; i32 accumulation exact. gate scale(s) = 2^(-15-8s).
// W packed gate-interleaved pc=4j+g: [panel][chunk32][d(3)][ks(2)][col(192)][16B].
// A packed [d(3)][slot=k/16][b][16B] (single buffer; kernel serialization = WAR safety).
// Tile 128x192, 12 waves (768 thr; wave: rows 32*(w&3), cols 64*(w>>2); acc[2][3]=96 VGPR).
// Grid 256 = 1 block/CU, 3 waves/SIMD (launch_bounds(768,3) caps ~170 VGPR).
// K-chunk 32, ring-4 LDS (4x30720B = 120KB), DEPTH-3 counted prefetch:
// [wait vmcnt(6/4)] [barrier] [STAGE(c+3)] [compute(c)]. Stage = 30 loads: waves 0-5
// issue 3, waves 6-11 issue 2 (per-wave-uniform vmcnt immediates).
// WAR: barrier at iter-c start orders iter-(c-1) reads before buf[(c+3)&3] reuse.
__global__ __launch_bounds__(768, 3)
void gemm_i8_kernel(const int8_t* __restrict__ Apack, const int8_t* __restrict__ Wpack,
                    const double* __restrict__ bsum, float* __restrict__ Gout, int K) {
    __shared__ int8_t lds8[122880];   // ring: 4 x 30720
    const int tid  = threadIdx.x;
    const int lane = tid & 63;
    const int w    = tid >> 6;        // 0..11

    const int orig = (int)blockIdx.x;
    const int wgid = (orig & 7) * 32 + (orig >> 3);   // XCD-bijective (256 = 32*8)
    const int b0 = (wgid & 7) * 128;
    const int panel = wgid >> 3;              // 0..31
    const int n0 = panel * 192;

    const int wr = w & 3;                     // row group 0..3
    const int wc = w >> 2;                    // col group 0..2
    const int lm = lane & 31;
    const int lh = lane >> 5;

    const int nc = K >> 5;                    // 48 (L0) or 96 (L1)
    const int8_t* Wp = Wpack + (size_t)panel * nc * 18432;

    i32x16 acc[2][3];
#pragma unroll
    for (int cf = 0; cf < 2; cf++)
#pragma unroll
        for (int s = 0; s < 3; s++)
            acc[cf][s] = (i32x16){0,0,0,0,0,0,0,0,0,0,0,0,0,0,0,0};

    // stage one 32-k chunk: 30 x 1KB contiguous loads; waves 0-5: 3, waves 6-11: 2
    auto STAGE = [&](int8_t* buf, int c) {
#pragma unroll
        for (int u = 0; u < 3; u++) {
            const int li = 12 * u + w;        // 0..35
            if (li >= 30) continue;
            if (li < 12) {                    // A: (d, ks, half)
                const int d = li >> 2, ks = (li >> 1) & 1, hf = li & 1;
                const int8_t* src = Apack + (size_t)d * APL3
                                  + (((size_t)(c * 2 + ks)) * 1024 + b0 + hf * 64 + lane) * 16;
                gload_lds16(src, buf + ((d * 2 + ks) * 128 + hf * 64) * 16);
            } else {                          // B: (d, ks, third)
                const int bli = li - 12;      // 0..17
                const int d = bli / 6, rem = bli % 6, ks = rem / 3, th = rem % 3;
                const int8_t* src = Wp + (size_t)c * 18432
                                  + ((d * 2 + ks) * 192 + th * 64 + lane) * 16;
                gload_lds16(src, buf + 12288 + ((d * 2 + ks) * 192 + th * 64) * 16);
            }
        }
    };

    STAGE(lds8, 0);
    STAGE(lds8 + 30720, 1);
    STAGE(lds8 + 61440, 2);

    for (int c = 0; c < nc; c++) {
        // wait until my chunk-c loads complete (newer chunks stay in flight)
        if (c + 3 <= nc) {                    // chunks c+1, c+2 still in flight
            if (w < 6) asm volatile("s_waitcnt vmcnt(6)" ::: "memory");
            else       asm volatile("s_waitcnt vmcnt(4)" ::: "memory");
        } else if (c + 2 == nc) {             // only chunk c+1 in flight
            if (w < 6) asm volatile("s_waitcnt vmcnt(3)" ::: "memory");
            else       asm volatile("s_waitcnt vmcnt(2)" ::: "memory");
        } else {
            asm volatile("s_waitcnt vmcnt(0)" ::: "memory");
        }
        __builtin_amdgcn_s_barrier();         // all waves: chunk-c in LDS; reads of c-1 done
        if (c + 3 < nc) STAGE(lds8 + ((c + 3) & 3) * 30720, c + 3);

        const int8_t* buf = lds8 + (c & 3) * 30720;
        i32x4 a0 = *(const i32x4*)(buf + ((0 * 2 + lh) * 128 + wr * 32 + lm) * 16);
        i32x4 a1 = *(const i32x4*)(buf + ((1 * 2 + lh) * 128 + wr * 32 + lm) * 16);
        i32x4 a2 = *(const i32x4*)(buf + ((2 * 2 + lh) * 128 + wr * 32 + lm) * 16);

        __builtin_amdgcn_s_setprio(1);
#pragma unroll
        for (int cf = 0; cf < 2; cf++) {
            const int bcol = wc * 64 + cf * 32 + lm;
            i32x4 b0v = *(const i32x4*)(buf + 12288 + ((0 * 2 + lh) * 192 + bcol) * 16);
            acc[cf][0] = __builtin_amdgcn_mfma_i32_32x32x32_i8(a0, b0v, acc[cf][0], 0, 0, 0);
            acc[cf][1] = __builtin_amdgcn_mfma_i32_32x32x32_i8(a1, b0v, acc[cf][1], 0, 0, 0);
            acc[cf][2] = __builtin_amdgcn_mfma_i32_32x32x32_i8(a2, b0v, acc[cf][2], 0, 0, 0);
            i32x4 b1v = *(const i32x4*)(buf + 12288 + ((1 * 2 + lh) * 192 + bcol) * 16);
            acc[cf][1] = __builtin_amdgcn_mfma_i32_32x32x32_i8(a0, b1v, acc[cf][1], 0, 0, 0);
            acc[cf][2] = __builtin_amdgcn_mfma_i32_32x32x32_i8(a1, b1v, acc[cf][2], 0, 0, 0);
            i32x4 b2v = *(const i32x4*)(buf + 12288 + ((2 * 2 + lh) * 192 + bcol) * 16);
            acc[cf][2] = __builtin_amdgcn_mfma_i32_32x32x32_i8(a0, b2v, acc[cf][2], 0, 0, 0);
        }
        __builtin_amdgcn_s_setprio(0);
    }

    // epilogue: C/D 32x32 layout (col=lane&31, row=(r&3)+8*(r>>2)+4*(lane>>5));
    // per (cf,r): 32 lanes write 32 consecutive f32 -> 128B coalesced stores.
#pragma unroll
    for (int cf = 0; cf < 2; cf++) {
        const int pc = n0 + wc * 64 + cf * 32 + lm;
        const double bb = bsum[pc];
#pragma unroll
        for (int r = 0; r < 16; r++) {
            const int row = b0 + wr * 32 + (r & 3) + 8 * (r >> 2) + 4 * lh;
            Gout[(size_t)row * G4dim + pc] = (float)(
                  (double)acc[cf][0][r] * 0x1p-15
                + (double)acc[cf][1][r] * 0x1p-23
                + (double)acc[cf][2][r] * 0x1p-31 + bb);
        }
    }
}

// ---------------- LSTM cell (i8 path): f32 gates, f32 c state, f32 transcendentals ----
__global__ __launch_bounds__(256)
void cell_i8_kernel(const float* __restrict__ G, float* __restrict__ c,
                    const float* __restrict__ Wg, const int* __restrict__ idx,
                    int useGather, int8_t* __restrict__ Apack, int koff) {
    int e = blockIdx.x * 256 + threadIdx.x;     // 0 .. B*H-1
    int b = e / Hdim, j = e - b * Hdim;
    const f32x4 gv = *(const f32x4*)(G + (size_t)b * G4dim + 4 * j);
    float gi = gv.x, gf = gv.y, gg = gv.z, go = gv.w;
    if (useGather) {
        const f32x4 wv = *(const f32x4*)(Wg + (size_t)idx[b] * G4dim + 4 * j);
        gi += wv.x; gf += wv.y; gg += wv.z; go += wv.w;
    }
    float si = 1.0f / (1.0f + expf(-gi));
    float sf = 1.0f / (1.0f + expf(-gf));
    float tg = tanhf(gg);
    float so = 1.0f / (1.0f + expf(-go));
    float cn = sf * c[e] + si * tg;
    c[e] = cn;
    float hn = so * tanhf(cn);
    int X = __float2int_rn(hn * 4194304.0f);    // h * 2^22, |h| <= 1
    int8_t q0, q1, q2;
    digits3(X, q0, q1, q2);
    const int slot = (koff + j) >> 4, byte = j & 15;
    const size_t ab = ((size_t)slot * 1024 + b) * 16 + byte;
    Apack[ab]            = q0;
    Apack[APL3 + ab]     = q1;
    Apack[2 * APL3 + ab] = q2;
}

// ======== i8 logits GEMM (3-digit, 6 products, packed): Lpart[ksp][b][v] (f32) ========
__global__ __launch_bounds__(256)
void logits_i8_kernel(const int8_t* __restrict__ Apack, const int8_t* __restrict__ Wodp,
                      float* __restrict__ Lpart) {
    __shared__ int8_t lds8[24576];
    const int tid  = threadIdx.x;
    const int lane = tid & 63;
    const int w    = tid >> 6;
    const int b0   = blockIdx.x * 64;
    const int p    = blockIdx.y;
    const int ksp  = blockIdx.z;

    const int rh = w & 1;
    const int cw = w >> 1;
    const int lm = lane & 31;
    const int lh = lane >> 5;

    i32x16 acc[3];
#pragma unroll
    for (int s = 0; s < 3; s++)
        acc[s] = (i32x16){0,0,0,0,0,0,0,0,0,0,0,0,0,0,0,0};

    for (int c = 0; c < 6; c++) {
        __syncthreads();
#pragma unroll
        for (int u = 0; u < 6; u++) {
            const int li = 4 * u + w;     // 0..23
            if (li < 12) {
                const int d = li >> 2, ks = li & 3;
                const int slot = 96 + ksp * 24 + c * 4 + ks;
                const int8_t* src = Apack + (size_t)d * APL3
                                  + ((size_t)slot * 1024 + b0 + lane) * 16;
                gload_lds16(src, lds8 + li * 1024);
            } else {
                const int bli = li - 12;
                const int d = bli >> 2, ks = bli & 3;
                const int seg = ((p * 24 + ksp * 6 + c) * 3 + d) * 4 + ks;
                const int8_t* src = Wodp + ((size_t)seg * 64 + lane) * 16;
                gload_lds16(src, lds8 + 12288 + bli * 1024);
            }
        }
        __syncthreads();

#pragma unroll
        for (int kk = 0; kk < 2; kk++) {
            const int ks = 2 * kk + lh;
            i32x4 a[3], bb[3];
#pragma unroll
            for (int d = 0; d < 3; d++) {
                a[d]  = *(const i32x4*)(lds8 + ((d * 4 + ks) * 64 + rh * 32 + lm) * 16);
                bb[d] = *(const i32x4*)(lds8 + 12288 + ((d * 4 + ks) * 64 + cw * 32 + lm) * 16);
            }
            acc[0] = __builtin_amdgcn_mfma_i32_32x32x32_i8(a[0], bb[0], acc[0], 0, 0, 0);
            acc[1] = __builtin_amdgcn_mfma_i32_32x32x32_i8(a[0], bb[1], acc[1], 0, 0, 0);
            acc[1] = __builtin_amdgcn_mfma_i32_32x32x32_i8(a[1], bb[0], acc[1], 0, 0, 0);
            acc[2] = __builtin_amdgcn_mfma_i32_32x32x32_i8(a[0], bb[2], acc[2], 0, 0, 0);
            acc[2] = __builtin_amdgcn_mfma_i32_32x32x32_i8(a[1], bb[1], acc[2], 0, 0, 0);
            acc[2] = __builtin_amdgcn_mfma_i32_32x32x32_i8(a[2], bb[0], acc[2], 0, 0, 0);
        }
    }

    const int col = p * 64 + cw * 32 + lm;
#pragma unroll
    for (int r = 0; r < 16; r++) {
        const int row = b0 + rh * 32 + (r & 3) + 8 * (r >> 2) + 4 * lh;
        const double g = (double)acc[0][r] * 0x1p-15
                       + (double)acc[1][r] * 0x1p-23
                       + (double)acc[2][r] * 0x1p-31;
        Lpart[((size_t)ksp * Bdim + row) * Vdim + col] = (float)g;
    }
}

// ---- gate-W 3-digit quantization, gate-interleaved packed (pc = 4j+g), chunk32 ----
__global__ __launch_bounds__(256)
void wquant_gate_kernel(const float* __restrict__ W, int8_t* __restrict__ out,
                        int col0, int NCH, int total4) {
    int t = blockIdx.x * 256 + threadIdx.x;
    if (t >= total4) return;
    int n = (4 * t) / Hdim, k = (4 * t) % Hdim;
    f32x4 wv = *(const f32x4*)(W + (size_t)n * Hdim + k);
    uint32_t pk[3] = {0, 0, 0};
#pragma unroll
    for (int l = 0; l < 4; l++) {
        double x = (double)wv[l] * 33554432.0;     // w * 2^25
        x = fmin(fmax(x, -8323072.0), 8323072.0);
        int X = __double2int_rn(x);
        int8_t e0, e1, e2;
        digits3(X, e0, e1, e2);
        pk[0] |= ((uint32_t)(uint8_t)e0) << (8 * l);
        pk[1] |= ((uint32_t)(uint8_t)e1) << (8 * l);
        pk[2] |= ((uint32_t)(uint8_t)e2) << (8 * l);
    }
    const int pcol = 4 * (n % 1536) + n / 1536;
    const int p = pcol / 192, col = pcol % 192;
    const int kk = col0 + k;
    const int c = kk >> 5, ks = (kk >> 4) & 1, byte = kk & 15;
#pragma unroll
    for (int d = 0; d < 3; d++) {
        size_t off = ((size_t)(p * NCH + c) * 6 + d * 2 + ks) * 3072 + col * 16 + byte;
        *(uint32_t*)(out + off) = pk[d];
    }
}

// ---- W_out 3-digit quantization into packed layout ----
__global__ __launch_bounds__(256)
void wquant_out_kernel(const float* __restrict__ W, int8_t* __restrict__ out, int total4) {
    int t = blockIdx.x * 256 + threadIdx.x;
    if (t >= total4) return;
    int n = (4 * t) / Hdim, k = (4 * t) % Hdim;
    f32x4 wv = *(const f32x4*)(W + (size_t)n * Hdim + k);
    uint32_t pk[3] = {0, 0, 0};
#pragma unroll
    for (int l = 0; l < 4; l++) {
        double x = (double)wv[l] * 33554432.0;
        x = fmin(fmax(x, -8323072.0), 8323072.0);
        int X = __double2int_rn(x);
        int8_t e0, e1, e2;
        digits3(X, e0, e1, e2);
        pk[0] |= ((uint32_t)(uint8_t)e0) << (8 * l);
        pk[1] |= ((uint32_t)(uint8_t)e1) << (8 * l);
        pk[2] |= ((uint32_t)(uint8_t)e2) << (8 * l);
    }
    const int p = n >> 6, col = n & 63;
    const int c = k >> 6, ks = (k >> 4) & 3, byte = k & 15;
#pragma unroll
    for (int d = 0; d < 3; d++) {
        size_t off = ((size_t)((p * 24 + c) * 3 + d) * 4 + ks) * 1024 + col * 16 + byte;
        *(uint32_t*)(out + off) = pk[d];
    }
}

// ---- bias pack: bs[4*j+g] = b1[g*H+j] + b2[g*H+j] ----
__global__ __launch_bounds__(256)
void biaspack_kernel(const float* __restrict__ b1, const float* __restrict__ b2,
                     double* __restrict__ bs) {
    int n = blockIdx.x * 256 + threadIdx.x;
    if (n >= G4dim) return;
    int g = n / Hdim, j = n % Hdim;
    bs[4 * j + g] = (double)b1[n] + (double)b2[n];
}

// ---- W_ih0 transpose into packed cols: Wt[v][4*j+g] = W[g*H+j][v] ----
__global__ __launch_bounds__(256)
void wtrans_kernel(const float* __restrict__ W, float* __restrict__ Wt) {
    __shared__ float tile[32][33];
    const int tx = threadIdx.x & 31, ty = threadIdx.x >> 5;
    const int r0 = blockIdx.x * 32;
    const int c0 = blockIdx.y * 32;
#pragma unroll
    for (int r = 0; r < 4; r++)
        tile[ty + 8 * r][tx] = W[(size_t)(r0 + ty + 8 * r) * Vdim + c0 + tx];
    __syncthreads();
    const int g = r0 / 1536;
#pragma unroll
    for (int r = 0; r < 4; r++) {
        const int n = r0 + tx;
        const int pc = 4 * (n % 1536) + g;
        Wt[(size_t)(c0 + ty + 8 * r) * G4dim + pc] = tile[tx][ty + 8 * r];
    }
}

// ---------------- LSTM cell pointwise update (fallback path only) ----------------
__global__ __launch_bounds__(256)
void cell_kernel(const double* __restrict__ G, double* __restrict__ c,
                 double* __restrict__ hout, const float* __restrict__ Wx,
                 const int* __restrict__ idx, int useGather) {
    int e = blockIdx.x * 256 + threadIdx.x;
    int b = e / Hdim, j = e - b * Hdim;
    size_t gb = (size_t)b * G4dim;
    double gi = G[gb + j];
    double gf = G[gb + Hdim + j];
    double gg = G[gb + 2 * Hdim + j];
    double go = G[gb + 3 * Hdim + j];
    if (useGather) {
        int id = idx[b];
        gi += (double)Wx[(size_t)(0 * Hdim + j) * Vdim + id];
        gf += (double)Wx[(size_t)(1 * Hdim + j) * Vdim + id];
        gg += (double)Wx[(size_t)(2 * Hdim + j) * Vdim + id];
        go += (double)Wx[(size_t)(3 * Hdim + j) * Vdim + id];
    }
    double si = 1.0 / (1.0 + exp(-gi));
    double sf = 1.0 / (1.0 + exp(-gf));
    double tg = tanh(gg);
    double so = 1.0 / (1.0 + exp(-go));
    double cn = sf * c[e] + si * tg;
    c[e] = cn;
    hout[e] = so * tanh(cn);
}

// ---- f64 vector GEMM (fallback noise t=0, plain cols) ----
__global__ __launch_bounds__(256)
void gemm_kernel(const float* __restrict__ A, const float* __restrict__ W,
                 double* __restrict__ C, int K) {
    __shared__ double As[16][65];
    __shared__ float  Wsf[16][68];
    const int tid = threadIdx.x;
    const int b0 = blockIdx.x * 64;
    const int n0 = blockIdx.y * 64;
    const int tm = tid >> 4;
    const int tn = tid & 15;

    double acc[4][4];
#pragma unroll
    for (int i = 0; i < 4; i++)
#pragma unroll
        for (int j = 0; j < 4; j++) acc[i][j] = 0.0;

    for (int k0 = 0; k0 < K; k0 += 16) {
        __syncthreads();
#pragma unroll
        for (int l = 0; l < 4; l++) {
            int e = tid + l * 256;
            int i = e >> 4, k = e & 15;
            As[k][i] = (double)A[(size_t)(b0 + i) * K + k0 + k];
            Wsf[k][i] = W[(size_t)(n0 + i) * K + k0 + k];
        }
        __syncthreads();
#pragma unroll
        for (int k = 0; k < 16; k++) {
            double a0 = As[k][tm * 4 + 0];
            double a1 = As[k][tm * 4 + 1];
            double a2 = As[k][tm * 4 + 2];
            double a3 = As[k][tm * 4 + 3];
            double w0 = (double)Wsf[k][tn * 4 + 0];
            double w1 = (double)Wsf[k][tn * 4 + 1];
            double w2 = (double)Wsf[k][tn * 4 + 2];
            double w3 = (double)Wsf[k][tn * 4 + 3];
            acc[0][0] = fma(a0, w0, acc[0][0]); acc[0][1] = fma(a0, w1, acc[0][1]);
            acc[0][2] = fma(a0, w2, acc[0][2]); acc[0][3] = fma(a0, w3, acc[0][3]);
            acc[1][0] = fma(a1, w0, acc[1][0]); acc[1][1] = fma(a1, w1, acc[1][1]);
            acc[1][2] = fma(a1, w2, acc[1][2]); acc[1][3] = fma(a1, w3, acc[1][3]);
            acc[2][0] = fma(a2, w0, acc[2][0]); acc[2][1] = fma(a2, w1, acc[2][1]);
            acc[2][2] = fma(a2, w2, acc[2][2]); acc[2][3] = fma(a2, w3, acc[2][3]);
            acc[3][0] = fma(a3, w0, acc[3][0]); acc[3][1] = fma(a3, w1, acc[3][1]);
            acc[3][2] = fma(a3, w2, acc[3][2]); acc[3][3] = fma(a3, w3, acc[3][3]);
        }
    }

#pragma unroll
    for (int i = 0; i < 4; i++) {
        int row = b0 + tm * 4 + i;
#pragma unroll
        for (int j = 0; j < 4; j++) {
            int col = n0 + tn * 4 + j;
            C[(size_t)row * G4dim + col] += acc[i][j];
        }
    }
}

// ---- f32 noise GEMM (i8 path, t=0): G[row][4j+g] += noise @ W_ih0^T ----
__global__ __launch_bounds__(256)
void gemm_noise_f32(const float* __restrict__ A, const float* __restrict__ W,
                    float* __restrict__ C, int K) {
    __shared__ double As[16][65];
    __shared__ float  Wsf[16][68];
    const int tid = threadIdx.x;
    const int b0 = blockIdx.x * 64;
    const int n0 = blockIdx.y * 64;
    const int tm = tid >> 4;
    const int tn = tid & 15;

    double acc[4][4];
#pragma unroll
    for (int i = 0; i < 4; i++)
#pragma unroll
        for (int j = 0; j < 4; j++) acc[i][j] = 0.0;

    for (int k0 = 0; k0 < K; k0 += 16) {
        __syncthreads();
#pragma unroll
        for (int l = 0; l < 4; l++) {
            int e = tid + l * 256;
            int i = e >> 4, k = e & 15;
            As[k][i] = (double)A[(size_t)(b0 + i) * K + k0 + k];
            Wsf[k][i] = W[(size_t)(n0 + i) * K + k0 + k];
        }
        __syncthreads();
#pragma unroll
        for (int k = 0; k < 16; k++) {
            double a0 = As[k][tm * 4 + 0];
            double a1 = As[k][tm * 4 + 1];
            double a2 = As[k][tm * 4 + 2];
            double a3 = As[k][tm * 4 + 3];
            double w0 = (double)Wsf[k][tn * 4 + 0];
            double w1 = (double)Wsf[k][tn * 4 + 1];
            double w2 = (double)Wsf[k][tn * 4 + 2];
            double w3 = (double)Wsf[k][tn * 4 + 3];
            acc[0][0] = fma(a0, w0, acc[0][0]); acc[0][1] = fma(a0, w1, acc[0][1]);
            acc[0][2] = fma(a0, w2, acc[0][2]); acc[0][3] = fma(a0, w3, acc[0][3]);
            acc[1][0] = fma(a1, w0, acc[1][0]); acc[1][1] = fma(a1, w1, acc[1][1]);
            acc[1][2] = fma(a1, w2, acc[1][2]); acc[1][3] = fma(a1, w3, acc[1][3]);
            acc[2][0] = fma(a2, w0, acc[2][0]); acc[2][1] = fma(a2, w1, acc[2][1]);
            acc[2][2] = fma(a2, w2, acc[2][2]); acc[2][3] = fma(a2, w3, acc[2][3]);
            acc[3][0] = fma(a3, w0, acc[3][0]); acc[3][1] = fma(a3, w1, acc[3][1]);
            acc[3][2] = fma(a3, w2, acc[3][2]); acc[3][3] = fma(a3, w3, acc[3][3]);
        }
    }

#pragma unroll
    for (int i = 0; i < 4; i++) {
        int row = b0 + tm * 4 + i;
#pragma unroll
        for (int j = 0; j < 4; j++) {
            int col = n0 + tn * 4 + j;
            int oc = 4 * (col % 1536) + col / 1536;
            C[(size_t)row * G4dim + oc] += (float)acc[i][j];
        }
    }
}

// -- light sampler: sum split-K partials (f32) + bias + gumbel + argmax --
__global__ __launch_bounds__(256)
void sample_lite_kernel(const float* __restrict__ Lpart, const float* __restrict__ bout,
                        const int* __restrict__ seqlen, int* __restrict__ idx,
                        int* __restrict__ out, int t) {
    __shared__ double rz[256];
    __shared__ int    rv[256];
    const int b = blockIdx.x;
    const int v = threadIdx.x;
    const size_t o = (size_t)b * Vdim + v;
    const size_t P = (size_t)Bdim * Vdim;

    double z = (double)Lpart[o] + (double)Lpart[P + o] + (double)Lpart[2 * P + o]
             + (double)Lpart[3 * P + o] + (double)bout[v];

    uint32_t kt0, kt1;
    tf2x32(0u, 42u, 0u, (uint32_t)t, kt0, kt1);
    uint32_t m = (uint32_t)(b * Vdim + v);
    uint32_t o0, o1;
    tf2x32(kt0, kt1, 0u, m, o0, o1);
    uint32_t bits = o0 ^ o1;
    float f = __uint_as_float((bits >> 9) | 0x3f800000u) - 1.0f;
    double u = (f > 0.f) ? (double)f : (double)1.1754943508222875e-38f;
    float gum32 = (float)(-log(-log(u)));
    z += (double)gum32;

    rz[v] = z; rv[v] = v;
    __syncthreads();
    for (int s = 128; s > 0; s >>= 1) {
        if (v < s) {
            double zo = rz[v + s]; int vo = rv[v + s];
            if (zo > rz[v] || (zo == rz[v] && vo < rv[v])) { rz[v] = zo; rv[v] = vo; }
        }
        __syncthreads();
    }
    if (v == 0) {
        int wv = rv[0];
        idx[b] = wv;
        out[(size_t)t * Bdim + b] = (t < seqlen[b]) ? wv : 0;
    }
}

// -- f64-path sampler (fallback) --
__global__ __launch_bounds__(256)
void sample_kernel(const double* __restrict__ h1, const float* __restrict__ Wout,
                   const float* __restrict__ bout, const int* __restrict__ seqlen,
                   int* __restrict__ idx, int* __restrict__ out, int t) {
    __shared__ double hs[Hdim];
    __shared__ float  Ws[256][33];
    __shared__ double rz[256];
    __shared__ int    rv[256];
    const int b = blockIdx.x;
    const int v = threadIdx.x;

    for (int k = v; k < Hdim; k += 256) hs[k] = h1[(size_t)b * Hdim + k];

    double acc = 0.0;
    for (int kc = 0; kc < Hdim; kc += 32) {
        __syncthreads();
#pragma unroll
        for (int l = 0; l < 32; l++) {
            int e = v + l * 256;
            int vv = e >> 5, kk = e & 31;
            Ws[vv][kk] = Wout[(size_t)vv * Hdim + kc + kk];
        }
        __syncthreads();
#pragma unroll
        for (int kk = 0; kk < 32; kk++)
            acc = fma((double)Ws[v][kk], hs[kc + kk], acc);
    }

    double z = acc + (double)bout[v];

    uint32_t kt0, kt1;
    tf2x32(0u, 42u, 0u, (uint32_t)t, kt0, kt1);
    uint32_t m = (uint32_t)(b * Vdim + v);
    uint32_t o0, o1;
    tf2x32(kt0, kt1, 0u, m, o0, o1);
    uint32_t bits = o0 ^ o1;
    float f = __uint_as_float((bits >> 9) | 0x3f800000u) - 1.0f;
    double u = (f > 0.f) ? (double)f : (double)1.1754943508222875e-38f;
    float gum32 = (float)(-log(-log(u)));
    z += (double)gum32;

    rz[v] = z; rv[v] = v;
    __syncthreads();
    for (int s = 128; s > 0; s >>= 1) {
        if (v < s) {
            double zo = rz[v + s]; int vo = rv[v + s];
            if (zo > rz[v] || (zo == rz[v] && vo < rv[v])) { rz[v] = zo; rv[v] = vo; }
        }
        __syncthreads();
    }
    if (v == 0) {
        int wv = rv[0];
        idx[b] = wv;
        out[(size_t)t * Bdim + b] = (t < seqlen[b]) ? wv : 0;
    }
}

// ---------------- diagnostic sentinel ----------------
__global__ void sentinel_kernel(int* out, int n, int val) {
    int i = blockIdx.x * 256 + threadIdx.x;
    if (i < n) out[i] = val;
}

// ---------------- host orchestration ----------------
extern "C" void kernel_launch(void* const* d_in, const int* in_sizes, int n_in,
                              void* d_out, int out_size, void* d_ws, size_t ws_size,
                              hipStream_t stream) {
    int* out = (int*)d_out;

    const size_t base_dbl = ((size_t)Bdim * G4dim + 4ull * Bdim * Hdim) * sizeof(double);
    const size_t misc = 8192;
    const size_t needed_f64 = base_dbl + misc;
    const size_t apk_sz   = 3ull * APL3;                         // 9.4 MB
    const size_t wd0_sz   = 3ull * G4dim * Hdim;                 // 28.3 MB
    const size_t wd1_sz   = 3ull * G4dim * (2 * Hdim);           // 56.6 MB
    const size_t wod_sz   = 3ull * Vdim * Hdim;                  // 1.18 MB
    const size_t lpart_sz = 4ull * Bdim * Vdim * sizeof(double); // 8.4 MB (f32 uses half)
    const size_t wt_sz    = (size_t)Vdim * G4dim * sizeof(float);// 6.3 MB
    const size_t bs_sz    = (size_t)G4dim * sizeof(double);
    const size_t needed_i8 = needed_f64 + apk_sz + wd0_sz + wd1_sz + wod_sz
                           + lpart_sz + wt_sz + 2 * bs_sz;

    if (ws_size < needed_f64) {
        sentinel_kernel<<<(out_size + 255) / 256, 256, 0, stream>>>(out, out_size, 1000000);
        return;
    }
    const int expect[12] = {Bdim * Vdim, Bdim, G4dim * Vdim, G4dim * Hdim, G4dim, G4dim,
                            G4dim * Hdim, G4dim * Hdim, G4dim, G4dim, Vdim * Hdim, Vdim};
    bool ok = (n_in == 12);
    for (int i = 0; ok && i < 12; i++) ok = (in_sizes[i] == expect[i]);
    if (!ok) {
        sentinel_kernel<<<(out_size + 255) / 256, 256, 0, stream>>>(out, out_size, 2000000);
        return;
    }

    const float* noise  = (const float*)d_in[0];
    const int*   seqlen = (const int*)d_in[1];
    const float* W_ih0  = (const float*)d_in[2];
    const float* W_hh0  = (const float*)d_in[3];
    const float* b_ih0  = (const float*)d_in[4];
    const float* b_hh0  = (const float*)d_in[5];
    const float* W_ih1  = (const float*)d_in[6];
    const float* W_hh1  = (const float*)d_in[7];
    const float* b_ih1  = (const float*)d_in[8];
    const float* b_hh1  = (const float*)d_in[9];
    const float* W_out  = (const float*)d_in[10];
    const float* b_out  = (const float*)d_in[11];

    double* G  = (double*)d_ws;
    double* h0 = G  + (size_t)Bdim * G4dim;
    double* c0 = h0 + (size_t)Bdim * Hdim;
    double* h1 = c0 + (size_t)Bdim * Hdim;
    double* c1 = h1 + (size_t)Bdim * Hdim;
    int*   idx = (int*)(c1 + (size_t)Bdim * Hdim);
    int*  lutAB = idx + Bdim;
    uint32_t* lutD = (uint32_t*)(lutAB + 64);
    int8_t* Apack = (int8_t*)(lutD + 64);
    int8_t* Wd0  = Apack + apk_sz;
    int8_t* Wd1  = Wd0 + wd0_sz;
    int8_t* Wod  = Wd1 + wd1_sz;
    double* Lpart = (double*)(Wod + wod_sz);
    float*  Wih0t = (float*)(Lpart + 4ull * Bdim * Vdim);
    double* bs0  = (double*)(Wih0t + (size_t)Vdim * G4dim);
    double* bs1  = bs0 + G4dim;

    float* Gf = (float*)G;              // i8 path uses G region as f32
    float* Lpf = (float*)Lpart;         // i8 path uses Lpart region as f32
    float* cf0 = (float*)c0;            // i8 path: f32 c state (region zeroed below)
    float* cf1 = (float*)c1;

    const bool use_i8 = (ws_size >= needed_i8);

    (void)hipMemsetAsync(h0, 0, (size_t)4 * Bdim * Hdim * sizeof(double), stream);

    dim3 gOld(Bdim / 64, G4dim / 64);

    if (use_i8) {
        (void)hipMemsetAsync(Apack, 0, apk_sz, stream);
        const int nq = G4dim * Hdim / 4;
        wquant_gate_kernel<<<(nq + 255) / 256, 256, 0, stream>>>(W_hh0, Wd0, 0, 48, nq);
        wquant_gate_kernel<<<(nq + 255) / 256, 256, 0, stream>>>(W_ih1, Wd1, 0, 96, nq);
        wquant_gate_kernel<<<(nq + 255) / 256, 256, 0, stream>>>(W_hh1, Wd1, Hdim, 96, nq);
        const int nqo = Vdim * Hdim / 4;
        wquant_out_kernel<<<(nqo + 255) / 256, 256, 0, stream>>>(W_out, Wod, nqo);
        wtrans_kernel<<<dim3(G4dim / 32, Vdim / 32), 256, 0, stream>>>(W_ih0, Wih0t);
        biaspack_kernel<<<G4dim / 256, 256, 0, stream>>>(b_ih0, b_hh0, bs0);
        biaspack_kernel<<<G4dim / 256, 256, 0, stream>>>(b_ih1, b_hh1, bs1);

        for (int t = 0; t < Tdim; t++) {
            // L0 gates: Gf[row][4j+g] = h0_old @ W_hh0^T + bias (f32, packed cols)
            gemm_i8_kernel<<<256, 768, 0, stream>>>(Apack, Wd0, bs0, Gf, Hdim);
            if (t == 0)   // x = noise: f64-acc GEMM adds into packed f32 G, once
                gemm_noise_f32<<<gOld, 256, 0, stream>>>(noise, W_ih0, Gf, Vdim);
            // cell L0: f32 gates + gather + f32 activations; writes h0 digits (slots 0..95)
            cell_i8_kernel<<<Bdim * Hdim / 256, 256, 0, stream>>>(Gf, cf0, Wih0t, idx,
                                                                  t > 0 ? 1 : 0, Apack, 0);
            // L1 gates: h0_new (slots 0..95) | h1_old (slots 96..191), K=3072 merged
            gemm_i8_kernel<<<256, 768, 0, stream>>>(Apack, Wd1, bs1, Gf, 2 * Hdim);
            // cell L1: writes h1 digits (slots 96..191)
            cell_i8_kernel<<<Bdim * Hdim / 256, 256, 0, stream>>>(Gf, cf1, nullptr, nullptr,
                                                                  0, Apack, Hdim);
            // logits via i8 split-K GEMM (f32 partials), then light sampler
            logits_i8_kernel<<<dim3(16, 4, 4), 256, 0, stream>>>(Apack, Wod, Lpf);
            sample_lite_kernel<<<Bdim, 256, 0, stream>>>(Lpf, b_out, seqlen, idx, out, t);
        }
    } else {
        mfma_probe_kernel<<<1, 64, 0, stream>>>(lutAB, lutD);
        dim3 gM(Bdim / 64, G4dim / 128);
        for (int t = 0; t < Tdim; t++) {
            gemm_mfma_kernel<<<gM, 256, 0, stream>>>(h0, h0, W_hh0, W_hh0, G, b_ih0, b_hh0,
                                                     lutAB, lutD, Hdim, 1);
            if (t == 0)
                gemm_kernel<<<gOld, 256, 0, stream>>>(noise, W_ih0, G, Vdim);
            cell_kernel<<<Bdim * Hdim / 256, 256, 0, stream>>>(G, c0, h0, W_ih0, idx,
                                                               t > 0 ? 1 : 0);
            gemm_mfma_kernel<<<gM, 256, 0, stream>>>(h0, h1, W_ih1, W_hh1, G, b_ih1, b_hh1,
                                                     lutAB, lutD, Hdim, 2);
            cell_kernel<<<Bdim * Hdim / 256, 256, 0, stream>>>(G, c1, h1, nullptr, nullptr, 0);
            sample_kernel<<<Bdim, 256, 0, stream>>>(h1, W_out, b_out, seqlen, idx, out, t);
        }
    }
}